// Round 5
// baseline (481.186 us; speedup 1.0000x reference)
//
#include <hip/hip_runtime.h>

#define D 128
#define BSZ 128            // dst nodes per bucket
#define CHUNK 8192         // edges per bucket_scatter block

typedef __attribute__((ext_vector_type(8))) short short8;
typedef __attribute__((ext_vector_type(4))) float f32x4;

__device__ inline float b2f(unsigned short u) {
    union { unsigned int u; float f; } x; x.u = ((unsigned int)u) << 16; return x.f;
}
__device__ inline unsigned short f2b(float f) {
    union { float f; unsigned int u; } x; x.f = f;
    unsigned int r = x.u + 0x7FFFu + ((x.u >> 16) & 1u);
    return (unsigned short)(r >> 16);
}

// ---------------------------------------------------------------------------
// phase1 (fused): h fp32->bf16 conversion | W fragment packing | bias sum |
// node-degree histograms. Independent work, dispatched by block range.
// ---------------------------------------------------------------------------
__global__ __launch_bounds__(256) void phase1(
    const float* __restrict__ hU, const float* __restrict__ hI,
    int nU8, int nI8,
    unsigned short* __restrict__ hbU, unsigned short* __restrict__ hbI,
    const float* __restrict__ Wself_uu, const float* __restrict__ Wself_iu,
    const float* __restrict__ Wneigh_uu, const float* __restrict__ Wneigh_iu,
    const float* __restrict__ Wself_ui, const float* __restrict__ Wneigh_ui,
    short8* __restrict__ WfU0, short8* __restrict__ WfU1, short8* __restrict__ WfU2,
    short8* __restrict__ WfI0, short8* __restrict__ WfI1,
    const float* __restrict__ b_uu, const float* __restrict__ b_iu,
    float* __restrict__ bsum,
    const int* __restrict__ d_uu, int E_uu,
    const int* __restrict__ d_iu, int E_iu,
    const int* __restrict__ d_ui, int E_ui,
    int* __restrict__ degUU, int* __restrict__ degIU, int* __restrict__ degUI,
    int nConvH)
{
    const int b = blockIdx.x;
    const int t = threadIdx.x;

    if (b < nConvH) {
        int g = b * 256 + t;
        const float* src; unsigned short* dst;
        if (g < nU8) { src = hU + (size_t)g * 8; dst = hbU + (size_t)g * 8; }
        else {
            g -= nU8;
            if (g >= nI8) return;
            src = hI + (size_t)g * 8; dst = hbI + (size_t)g * 8;
        }
        const float4 a = *reinterpret_cast<const float4*>(src);
        const float4 c = *reinterpret_cast<const float4*>(src + 4);
        short8 o;
        o[0] = (short)f2b(a.x); o[1] = (short)f2b(a.y);
        o[2] = (short)f2b(a.z); o[3] = (short)f2b(a.w);
        o[4] = (short)f2b(c.x); o[5] = (short)f2b(c.y);
        o[6] = (short)f2b(c.z); o[7] = (short)f2b(c.w);
        *reinterpret_cast<short8*>(dst) = o;
        return;
    }
    const int wb = b - nConvH;
    if (wb < 40) {
        const float* Wa; const float* Wb = nullptr; short8* Wf;
        switch (wb >> 3) {
            case 0: Wa = Wself_uu; Wb = Wself_iu; Wf = WfU0; break;
            case 1: Wa = Wneigh_uu; Wf = WfU1; break;
            case 2: Wa = Wneigh_iu; Wf = WfU2; break;
            case 3: Wa = Wself_ui;  Wf = WfI0; break;
            default: Wa = Wneigh_ui; Wf = WfI1; break;
        }
        int t2 = (wb & 7) * 256 + t;            // 0..2047
        int c  = t2 >> 8;
        int kc = (t2 >> 6) & 3;
        int l  = t2 & 63;
        int n  = c * 16 + (l & 15);
        int k0 = kc * 32 + ((l >> 4) << 3);
        short8 o;
#pragma unroll
        for (int j = 0; j < 8; ++j) {
            float v = Wa[(k0 + j) * D + n];
            if (Wb) v += Wb[(k0 + j) * D + n];
            o[j] = (short)f2b(v);
        }
        Wf[t2] = o;
        return;
    }
    if (wb == 40) {
        if (t < D) bsum[t] = b_uu[t] + b_iu[t];
        return;
    }
    // node-degree histogram: 4 edges per thread over concatenated lists
    const int ET = E_uu + E_iu + E_ui;
    int e0 = (wb - 41) * 1024 + t * 4;
#pragma unroll
    for (int j = 0; j < 4; ++j) {
        int e = e0 + j;
        if (e >= ET) return;
        if (e < E_uu)               atomicAdd(&degUU[d_uu[e]], 1);
        else if (e < E_uu + E_iu)   atomicAdd(&degIU[d_iu[e - E_uu]], 1);
        else                        atomicAdd(&degUI[d_ui[e - E_uu - E_iu]], 1);
    }
}

// ---------------------------------------------------------------------------
// bucket_sum: counts[b] = sum of node degrees in bucket b (one wave/bucket).
// ---------------------------------------------------------------------------
__global__ __launch_bounds__(256) void bucket_sum_kernel(
    const int* __restrict__ degUU, const int* __restrict__ degIU,
    const int* __restrict__ degUI,
    int NB0, int NB1, int NB2, int NU, int NI, int* __restrict__ counts)
{
    int wid  = (blockIdx.x * 256 + threadIdx.x) >> 6;
    int lane = threadIdx.x & 63;
    int NBT = NB0 + NB1 + NB2;
    if (wid >= NBT) return;
    const int* deg; int N; int lb;
    if (wid < NB0)            { lb = wid;             deg = degUU; N = NU; }
    else if (wid < NB0 + NB1) { lb = wid - NB0;       deg = degIU; N = NU; }
    else                      { lb = wid - NB0 - NB1; deg = degUI; N = NI; }
    int n0 = lb * BSZ;
    int s = 0;
    if (n0 + lane      < N) s += deg[n0 + lane];
    if (n0 + 64 + lane < N) s += deg[n0 + 64 + lane];
#pragma unroll
    for (int off = 32; off; off >>= 1) s += __shfl_down(s, off);
    if (lane == 0) counts[wid] = s;
}

// ---------------------------------------------------------------------------
// scan: exclusive scan of counts[NBT] -> bb[NBT+1]; cursors = copy of bases.
// Single block, 1024 threads, 2 values/thread (NBT <= 2048).
// ---------------------------------------------------------------------------
__global__ __launch_bounds__(1024) void scan_kernel(
    const int* __restrict__ counts, int NBT,
    int* __restrict__ bb, int* __restrict__ cur)
{
    __shared__ int s[1024];
    int t = threadIdx.x;
    int i0 = t * 2, i1 = t * 2 + 1;
    int v0 = (i0 < NBT) ? counts[i0] : 0;
    int v1 = (i1 < NBT) ? counts[i1] : 0;
    int sum = v0 + v1;
    s[t] = sum;
    __syncthreads();
    for (int off = 1; off < 1024; off <<= 1) {
        int x = (t >= off) ? s[t - off] : 0;
        __syncthreads();
        s[t] += x;
        __syncthreads();
    }
    int pre = s[t] - sum;   // exclusive prefix
    if (i0 < NBT) { bb[i0] = pre;      cur[i0] = pre; }
    if (i1 < NBT) { bb[i1] = pre + v0; cur[i1] = pre + v0; }
    if (t == 1023) bb[NBT] = s[1023];
}

// ---------------------------------------------------------------------------
// bucket_scatter: group edges by 128-dst bucket into staging (packed int:
// src | dstLocal<<17). Block-aggregated reservation -> semi-coalesced runs.
// ---------------------------------------------------------------------------
__global__ __launch_bounds__(256) void bucket_scatter(
    const int* __restrict__ s_uu, const int* __restrict__ d_uu, int E_uu,
    const int* __restrict__ s_iu, const int* __restrict__ d_iu, int E_iu,
    const int* __restrict__ s_ui, const int* __restrict__ d_ui, int E_ui,
    int NB0, int NB1,
    int* __restrict__ cursors, int* __restrict__ staging,
    int nblk0, int nblk1)
{
    __shared__ int hist[512];
    __shared__ int bbase[512];

    const int* src; const int* dst; int E; int relBase; int b0;
    if (blockIdx.x < nblk0) {
        b0 = blockIdx.x; src = s_uu; dst = d_uu; E = E_uu; relBase = 0;
    } else if (blockIdx.x < nblk0 + nblk1) {
        b0 = blockIdx.x - nblk0; src = s_iu; dst = d_iu; E = E_iu; relBase = NB0;
    } else {
        b0 = blockIdx.x - nblk0 - nblk1; src = s_ui; dst = d_ui; E = E_ui;
        relBase = NB0 + NB1;
    }
    const int t = threadIdx.x;
    const int e0 = b0 * CHUNK;

    for (int i = t; i < 512; i += 256) hist[i] = 0;
    __syncthreads();

#pragma unroll
    for (int j = 0; j < CHUNK / 256; ++j) {
        int e = e0 + j * 256 + t;
        if (e < E) atomicAdd(&hist[dst[e] >> 7], 1);
    }
    __syncthreads();

    for (int b = t; b < 512; b += 256) {
        int c = hist[b];
        bbase[b] = c ? atomicAdd(&cursors[relBase + b], c) : 0;
        hist[b] = 0;    // reuse as rank counter
    }
    __syncthreads();

#pragma unroll
    for (int j = 0; j < CHUNK / 256; ++j) {
        int e = e0 + j * 256 + t;
        if (e < E) {
            int dv = dst[e];
            int bkt = dv >> 7;
            int r = atomicAdd(&hist[bkt], 1);
            staging[bbase[bkt] + r] = (src[e] & 0x1FFFF) | ((dv & 127) << 17);
        }
    }
}

// ---------------------------------------------------------------------------
// gather_bucketed: one block per bucket; 4 waves x 32 dsts, wave-private
// 16KB f32 LDS accumulators (no __syncthreads). Ballot-filtered edges,
// 4 h-row loads batched in flight. Writes bf16 means.
// ---------------------------------------------------------------------------
__global__ __launch_bounds__(256) void gather_bucketed(
    const unsigned short* __restrict__ hbU, const unsigned short* __restrict__ hbI,
    const int* __restrict__ staging, const int* __restrict__ bb,
    const int* __restrict__ degUU, const int* __restrict__ degIU,
    const int* __restrict__ degUI,
    unsigned short* __restrict__ accUU, unsigned short* __restrict__ accIU,
    unsigned short* __restrict__ accUI,
    int NB0, int NB1, int NU, int NI)
{
    __shared__ float acc[4][32][128];   // 64 KB, wave-private segments

    const int b = blockIdx.x;
    const unsigned short* hb; const int* deg; unsigned short* out; int N; int lb;
    if (b < NB0)            { lb = b;             hb = hbU; deg = degUU; out = accUU; N = NU; }
    else if (b < NB0 + NB1) { lb = b - NB0;       hb = hbI; deg = degIU; out = accIU; N = NU; }
    else                    { lb = b - NB0 - NB1; hb = hbU; deg = degUI; out = accUI; N = NI; }

    const int t = threadIdx.x;
    const int w = t >> 6, lane = t & 63;
    const int mylo = w * 32;
    const int node0 = lb * BSZ;

    // zero my wave's accumulator segment (1024 float4)
    float4* az = reinterpret_cast<float4*>(&acc[w][0][0]);
    for (int i = lane; i < 1024; i += 64) az[i] = make_float4(0.f, 0.f, 0.f, 0.f);

    const int lo = bb[b], hi = bb[b + 1];

    for (int base = lo; base < hi; base += 64) {
        int idx = base + lane;
        int v = (idx < hi) ? staging[idx] : -1;
        int dstl = (v >> 17) & 127;
        int srcn = v & 0x1FFFF;
        bool mine = (v >= 0) && (dstl >= mylo) && (dstl < mylo + 32);
        unsigned long long mask = __ballot(mine);
        while (mask) {
            unsigned int hv[4]; int dl[4]; int nb = 0;
#pragma unroll
            for (int q = 0; q < 4; ++q) {
                if (mask) {
                    int j = __ffsll(mask) - 1; mask &= mask - 1;
                    int sj = __shfl(srcn, j);
                    dl[nb] = __shfl(dstl, j);
                    hv[nb] = *reinterpret_cast<const unsigned int*>(
                        hb + (size_t)sj * D + lane * 2);
                    ++nb;
                }
            }
#pragma unroll
            for (int q = 0; q < 4; ++q) {
                if (q < nb) {
                    float f0 = b2f((unsigned short)(hv[q] & 0xFFFF));
                    float f1 = b2f((unsigned short)(hv[q] >> 16));
                    float* a = &acc[w][dl[q] - mylo][lane * 2];
                    a[0] += f0; a[1] += f1;
                }
            }
        }
    }

    // write bf16 means for my 32 dst nodes
    for (int i = 0; i < 32; ++i) {
        int node = node0 + mylo + i;
        if (node >= N) break;
        float inv = 1.0f / fmaxf((float)deg[node], 1.0f);
        float2 av = *reinterpret_cast<float2*>(&acc[w][i][lane * 2]);
        unsigned int pk = (unsigned int)f2b(av.x * inv)
                        | ((unsigned int)f2b(av.y * inv) << 16);
        *reinterpret_cast<unsigned int*>(out + (size_t)node * D + lane * 2) = pk;
    }
}

// ---------------------------------------------------------------------------
// GEMM (fused): both output types in one launch, branch on block range.
// out[N,128] = A0@W0 + A1@W1 [+ A2@W2] + bias; W* fragment-linear bf16.
// ---------------------------------------------------------------------------
__global__ __launch_bounds__(512) void gemm_all(
    const unsigned short* __restrict__ hbU,
    const unsigned short* __restrict__ accUU, const unsigned short* __restrict__ accIU,
    const short8* __restrict__ WfU0, const short8* __restrict__ WfU1,
    const short8* __restrict__ WfU2, const float* __restrict__ bsum,
    const unsigned short* __restrict__ hbI, const unsigned short* __restrict__ accUI,
    const short8* __restrict__ WfI0, const short8* __restrict__ WfI1,
    const float* __restrict__ b_ui,
    float* __restrict__ outU, float* __restrict__ outI,
    int NU, int NI, int nBlkU)
{
    __shared__ short8 lds[2048];     // 32 KB: one fragment-linear W
    const int t = threadIdx.x;
    const int w = t >> 6, l = t & 63;

    const unsigned short *A0, *A1, *A2;
    const short8 *W0, *W1, *W2;
    const float* bias; float* out; int N; int blk;
    if (blockIdx.x < nBlkU) {
        blk = blockIdx.x;
        A0 = hbU; A1 = accUU; A2 = accIU;
        W0 = WfU0; W1 = WfU1; W2 = WfU2;
        bias = bsum; out = outU; N = NU;
    } else {
        blk = blockIdx.x - nBlkU;
        A0 = hbI; A1 = accUI; A2 = nullptr;
        W0 = WfI0; W1 = WfI1; W2 = nullptr;
        bias = b_ui; out = outI; N = NI;
    }

    const int row0 = blk * 128 + w * 16;
    const int arow = row0 + (l & 15);

    f32x4 acc[8];
#pragma unroll
    for (int c = 0; c < 8; ++c) acc[c] = (f32x4){0.f, 0.f, 0.f, 0.f};

    const unsigned short* As[3] = {A0, A1, A2};
    const short8* Wfs[3] = {W0, W1, W2};
    const int nsrc = (A2 != nullptr) ? 3 : 2;

    for (int sI = 0; sI < nsrc; ++sI) {
        __syncthreads();
        const short8* Wg = Wfs[sI];
#pragma unroll
        for (int i = 0; i < 4; ++i) lds[t + i * 512] = Wg[t + i * 512];
        __syncthreads();

        const unsigned short* A = As[sI];
        short8 af[4];
        if (arow < N) {
            const unsigned short* base = A + (size_t)arow * D + ((l >> 4) << 3);
#pragma unroll
            for (int kc = 0; kc < 4; ++kc)
                af[kc] = *reinterpret_cast<const short8*>(base + kc * 32);
        } else {
            short8 z = {0, 0, 0, 0, 0, 0, 0, 0};
#pragma unroll
            for (int kc = 0; kc < 4; ++kc) af[kc] = z;
        }
#pragma unroll
        for (int kc = 0; kc < 4; ++kc)
#pragma unroll
            for (int c = 0; c < 8; ++c)
                acc[c] = __builtin_amdgcn_mfma_f32_16x16x32_bf16(
                    af[kc], lds[(c * 4 + kc) * 64 + l], acc[c], 0, 0, 0);
    }

    const int col = l & 15;
#pragma unroll
    for (int c = 0; c < 8; ++c) {
        float bv = bias[c * 16 + col];
#pragma unroll
        for (int r = 0; r < 4; ++r) {
            int row = row0 + ((l >> 4) << 2) + r;
            if (row < N)
                out[(size_t)row * D + c * 16 + col] = acc[c][r] + bv;
        }
    }
}

// ---------------------------------------------------------------------------
extern "C" void kernel_launch(void* const* d_in, const int* in_sizes, int n_in,
                              void* d_out, int out_size, void* d_ws, size_t ws_size,
                              hipStream_t stream)
{
    const float* h_user    = (const float*)d_in[0];
    const float* h_item    = (const float*)d_in[1];
    const float* Wself_uu  = (const float*)d_in[2];
    const float* Wneigh_uu = (const float*)d_in[3];
    const float* b_uu      = (const float*)d_in[4];
    const float* Wself_ui  = (const float*)d_in[5];
    const float* Wneigh_ui = (const float*)d_in[6];
    const float* b_ui      = (const float*)d_in[7];
    const float* Wself_iu  = (const float*)d_in[8];
    const float* Wneigh_iu = (const float*)d_in[9];
    const float* b_iu      = (const float*)d_in[10];
    const int* e_uu_src    = (const int*)d_in[11];
    const int* e_uu_dst    = (const int*)d_in[12];
    const int* e_ui_src    = (const int*)d_in[13];
    const int* e_ui_dst    = (const int*)d_in[14];
    const int* e_iu_src    = (const int*)d_in[15];
    const int* e_iu_dst    = (const int*)d_in[16];

    const int NU = in_sizes[0] / D;
    const int NI = in_sizes[1] / D;
    const int E_uu = in_sizes[11];
    const int E_ui = in_sizes[13];
    const int E_iu = in_sizes[15];
    const int ET = E_uu + E_iu + E_ui;

    const int NB0 = (NU + BSZ - 1) / BSZ;   // uu (dst=user)
    const int NB1 = (NU + BSZ - 1) / BSZ;   // iu (dst=user)
    const int NB2 = (NI + BSZ - 1) / BSZ;   // ui (dst=item)
    const int NBT = NB0 + NB1 + NB2;

    // ---- workspace carve-up (16B-aligned chunks) ----
    char* p = (char*)d_ws;
    unsigned short* hbU   = (unsigned short*)p; p += (size_t)NU * D * 2;
    unsigned short* hbI   = (unsigned short*)p; p += (size_t)NI * D * 2;
    unsigned short* accUU = (unsigned short*)p; p += (size_t)NU * D * 2;
    unsigned short* accIU = (unsigned short*)p; p += (size_t)NU * D * 2;
    unsigned short* accUI = (unsigned short*)p; p += (size_t)NI * D * 2;
    short8* WfU0 = (short8*)p; p += 32768;
    short8* WfU1 = (short8*)p; p += 32768;
    short8* WfU2 = (short8*)p; p += 32768;
    short8* WfI0 = (short8*)p; p += 32768;
    short8* WfI1 = (short8*)p; p += 32768;
    float* bsum  = (float*)p;  p += 512;
    int* degUU = (int*)p; p += (size_t)NU * 4;
    int* degIU = (int*)p; p += (size_t)NU * 4;
    int* degUI = (int*)p; p += (size_t)NI * 4;
    int* counts  = (int*)p; p += (size_t)((NBT + 3) & ~3) * 4;
    int* bb      = (int*)p; p += (size_t)((NBT + 4) & ~3) * 4;
    int* cursors = (int*)p; p += (size_t)((NBT + 3) & ~3) * 4;
    int* staging = (int*)p; p += (size_t)ET * 4;

    // zero the node-degree counters only
    hipMemsetAsync(degUU, 0, (size_t)(2 * NU + NI) * sizeof(int), stream);

    const int nU8 = NU * D / 8, nI8 = NI * D / 8;
    const int nConvH = (nU8 + nI8 + 255) / 256;
    const int nHist  = (ET + 1023) / 1024;

    phase1<<<nConvH + 41 + nHist, 256, 0, stream>>>(
        h_user, h_item, nU8, nI8, hbU, hbI,
        Wself_uu, Wself_iu, Wneigh_uu, Wneigh_iu, Wself_ui, Wneigh_ui,
        WfU0, WfU1, WfU2, WfI0, WfI1,
        b_uu, b_iu, bsum,
        e_uu_dst, E_uu, e_iu_dst, E_iu, e_ui_dst, E_ui,
        degUU, degIU, degUI, nConvH);

    bucket_sum_kernel<<<(NBT + 3) / 4, 256, 0, stream>>>(
        degUU, degIU, degUI, NB0, NB1, NB2, NU, NI, counts);

    scan_kernel<<<1, 1024, 0, stream>>>(counts, NBT, bb, cursors);

    const int nblk0 = (E_uu + CHUNK - 1) / CHUNK;
    const int nblk1 = (E_iu + CHUNK - 1) / CHUNK;
    const int nblk2 = (E_ui + CHUNK - 1) / CHUNK;
    bucket_scatter<<<nblk0 + nblk1 + nblk2, 256, 0, stream>>>(
        e_uu_src, e_uu_dst, E_uu,
        e_iu_src, e_iu_dst, E_iu,
        e_ui_src, e_ui_dst, E_ui,
        NB0, NB1, cursors, staging, nblk0, nblk1);

    gather_bucketed<<<NBT, 256, 0, stream>>>(
        hbU, hbI, staging, bb, degUU, degIU, degUI,
        accUU, accIU, accUI, NB0, NB1, NU, NI);

    float* out_user = (float*)d_out;
    float* out_item = out_user + (size_t)NU * D;
    const int nBlkU = (NU + 127) / 128, nBlkI = (NI + 127) / 128;

    gemm_all<<<nBlkU + nBlkI, 512, 0, stream>>>(
        hbU, accUU, accIU, WfU0, WfU1, WfU2, bsum,
        hbI, accUI, WfI0, WfI1, b_ui,
        out_user, out_item, NU, NI, nBlkU);
}

// Round 6
// 249.985 us; speedup vs baseline: 1.9249x; 1.9249x over previous
//
#include <hip/hip_runtime.h>

#define D 128
#define BSZ 128            // dst nodes per bucket
#define CHUNK 8192         // edges per bucket_scatter block

typedef __attribute__((ext_vector_type(8))) short short8;
typedef __attribute__((ext_vector_type(4))) float f32x4;

__device__ inline float b2f(unsigned short u) {
    union { unsigned int u; float f; } x; x.u = ((unsigned int)u) << 16; return x.f;
}
__device__ inline unsigned short f2b(float f) {
    union { float f; unsigned int u; } x; x.f = f;
    unsigned int r = x.u + 0x7FFFu + ((x.u >> 16) & 1u);
    return (unsigned short)(r >> 16);
}

// ---------------------------------------------------------------------------
// phase1 (fused): h fp32->bf16 conversion | W fragment packing | bias sum |
// node-degree histograms. Independent work, dispatched by block range.
// ---------------------------------------------------------------------------
__global__ __launch_bounds__(256) void phase1(
    const float* __restrict__ hU, const float* __restrict__ hI,
    int nU8, int nI8,
    unsigned short* __restrict__ hbU, unsigned short* __restrict__ hbI,
    const float* __restrict__ Wself_uu, const float* __restrict__ Wself_iu,
    const float* __restrict__ Wneigh_uu, const float* __restrict__ Wneigh_iu,
    const float* __restrict__ Wself_ui, const float* __restrict__ Wneigh_ui,
    short8* __restrict__ WfU0, short8* __restrict__ WfU1, short8* __restrict__ WfU2,
    short8* __restrict__ WfI0, short8* __restrict__ WfI1,
    const float* __restrict__ b_uu, const float* __restrict__ b_iu,
    float* __restrict__ bsum,
    const int* __restrict__ d_uu, int E_uu,
    const int* __restrict__ d_iu, int E_iu,
    const int* __restrict__ d_ui, int E_ui,
    int* __restrict__ degUU, int* __restrict__ degIU, int* __restrict__ degUI,
    int nConvH)
{
    const int b = blockIdx.x;
    const int t = threadIdx.x;

    if (b < nConvH) {
        int g = b * 256 + t;
        const float* src; unsigned short* dst;
        if (g < nU8) { src = hU + (size_t)g * 8; dst = hbU + (size_t)g * 8; }
        else {
            g -= nU8;
            if (g >= nI8) return;
            src = hI + (size_t)g * 8; dst = hbI + (size_t)g * 8;
        }
        const float4 a = *reinterpret_cast<const float4*>(src);
        const float4 c = *reinterpret_cast<const float4*>(src + 4);
        short8 o;
        o[0] = (short)f2b(a.x); o[1] = (short)f2b(a.y);
        o[2] = (short)f2b(a.z); o[3] = (short)f2b(a.w);
        o[4] = (short)f2b(c.x); o[5] = (short)f2b(c.y);
        o[6] = (short)f2b(c.z); o[7] = (short)f2b(c.w);
        *reinterpret_cast<short8*>(dst) = o;
        return;
    }
    const int wb = b - nConvH;
    if (wb < 40) {
        const float* Wa; const float* Wb = nullptr; short8* Wf;
        switch (wb >> 3) {
            case 0: Wa = Wself_uu; Wb = Wself_iu; Wf = WfU0; break;
            case 1: Wa = Wneigh_uu; Wf = WfU1; break;
            case 2: Wa = Wneigh_iu; Wf = WfU2; break;
            case 3: Wa = Wself_ui;  Wf = WfI0; break;
            default: Wa = Wneigh_ui; Wf = WfI1; break;
        }
        int t2 = (wb & 7) * 256 + t;            // 0..2047
        int c  = t2 >> 8;
        int kc = (t2 >> 6) & 3;
        int l  = t2 & 63;
        int n  = c * 16 + (l & 15);
        int k0 = kc * 32 + ((l >> 4) << 3);
        short8 o;
#pragma unroll
        for (int j = 0; j < 8; ++j) {
            float v = Wa[(k0 + j) * D + n];
            if (Wb) v += Wb[(k0 + j) * D + n];
            o[j] = (short)f2b(v);
        }
        Wf[t2] = o;
        return;
    }
    if (wb == 40) {
        if (t < D) bsum[t] = b_uu[t] + b_iu[t];
        return;
    }
    // node-degree histogram: 4 edges per thread over concatenated lists
    const int ET = E_uu + E_iu + E_ui;
    int e0 = (wb - 41) * 1024 + t * 4;
#pragma unroll
    for (int j = 0; j < 4; ++j) {
        int e = e0 + j;
        if (e >= ET) return;
        if (e < E_uu)               atomicAdd(&degUU[d_uu[e]], 1);
        else if (e < E_uu + E_iu)   atomicAdd(&degIU[d_iu[e - E_uu]], 1);
        else                        atomicAdd(&degUI[d_ui[e - E_uu - E_iu]], 1);
    }
}

// ---------------------------------------------------------------------------
// 3-phase exclusive scan over the 3 degree arrays (64 blocks per relation).
// After scanC, deg arrays hold exclusive START offsets (pristine CSR offs).
// scanC also emits bucket cursors: cursors[relBase + i/128] = offs[i] at
// i%128==0 (start position of each 128-node bucket).
// ---------------------------------------------------------------------------
__global__ __launch_bounds__(256) void scanA_kernel(
    int* d0, int n0, int* d1, int n1, int* d2, int n2, int* __restrict__ partials)
{
    int rel = blockIdx.x >> 6, blk = blockIdx.x & 63;
    int* d; int n;
    if (rel == 0)      { d = d0; n = n0; }
    else if (rel == 1) { d = d1; n = n1; }
    else               { d = d2; n = n2; }
    int chunk = (n + 63) >> 6;
    int lo = blk * chunk, hi = min(n, lo + chunk);
    int s = 0;
    for (int i = lo + threadIdx.x; i < hi; i += 256) s += d[i];
    __shared__ int red[256];
    red[threadIdx.x] = s;
    __syncthreads();
    for (int off = 128; off > 0; off >>= 1) {
        if (threadIdx.x < off) red[threadIdx.x] += red[threadIdx.x + off];
        __syncthreads();
    }
    if (threadIdx.x == 0) partials[rel * 64 + blk] = red[0];
}

__global__ __launch_bounds__(192) void scanB_kernel(int* __restrict__ partials)
{
    __shared__ int s[192];
    int t = threadIdx.x, i = t & 63;
    int v = partials[t];
    s[t] = v;
    __syncthreads();
    for (int off = 1; off < 64; off <<= 1) {
        int x = (i >= off) ? s[t - off] : 0;
        __syncthreads();
        s[t] += x;
        __syncthreads();
    }
    partials[t] = s[t] - v;   // exclusive
}

__global__ __launch_bounds__(256) void scanC_kernel(
    int* d0, int n0, int* d1, int n1, int* d2, int n2,
    const int* __restrict__ partials,
    int* __restrict__ cursors, int NB0, int NB1)
{
    int rel = blockIdx.x >> 6, blk = blockIdx.x & 63;
    int* d; int n; int cbase;
    if (rel == 0)      { d = d0; n = n0; cbase = 0; }
    else if (rel == 1) { d = d1; n = n1; cbase = NB0; }
    else               { d = d2; n = n2; cbase = NB0 + NB1; }
    int chunk = (n + 63) >> 6;
    int lo = blk * chunk, hi = min(n, lo + chunk);
    int sub = (chunk + 255) >> 8;
    int mylo = lo + threadIdx.x * sub;
    int myhi = min(hi, mylo + sub);
    int msum = 0;
    for (int i = mylo; i < myhi; ++i) msum += d[i];
    __shared__ int s[256];
    int t = threadIdx.x;
    s[t] = msum;
    __syncthreads();
    for (int off = 1; off < 256; off <<= 1) {
        int x = (t >= off) ? s[t - off] : 0;
        __syncthreads();
        s[t] += x;
        __syncthreads();
    }
    int run = partials[rel * 64 + blk] + s[t] - msum;
    for (int i = mylo; i < myhi; ++i) {
        int v = d[i];
        d[i] = run;
        if ((i & 127) == 0) cursors[cbase + (i >> 7)] = run;
        run += v;
    }
}

// ---------------------------------------------------------------------------
// bucket_scatter: group edges by 128-dst bucket into per-relation staging
// (packed int: src | dstLocal<<17) at the bucket's CSR window. Block-
// aggregated reservation -> semi-coalesced ~84B runs, no write blow-up.
// ---------------------------------------------------------------------------
__global__ __launch_bounds__(256) void bucket_scatter(
    const int* __restrict__ s_uu, const int* __restrict__ d_uu, int E_uu,
    const int* __restrict__ s_iu, const int* __restrict__ d_iu, int E_iu,
    const int* __restrict__ s_ui, const int* __restrict__ d_ui, int E_ui,
    int NB0, int NB1,
    int* __restrict__ cursors,
    int* __restrict__ stgUU, int* __restrict__ stgIU, int* __restrict__ stgUI,
    int nblk0, int nblk1)
{
    __shared__ int hist[512];
    __shared__ int bbase[512];

    const int* src; const int* dst; int E; int relBase; int b0; int* stg;
    if (blockIdx.x < nblk0) {
        b0 = blockIdx.x; src = s_uu; dst = d_uu; E = E_uu; relBase = 0; stg = stgUU;
    } else if (blockIdx.x < nblk0 + nblk1) {
        b0 = blockIdx.x - nblk0; src = s_iu; dst = d_iu; E = E_iu; relBase = NB0; stg = stgIU;
    } else {
        b0 = blockIdx.x - nblk0 - nblk1; src = s_ui; dst = d_ui; E = E_ui;
        relBase = NB0 + NB1; stg = stgUI;
    }
    const int t = threadIdx.x;
    const int e0 = b0 * CHUNK;

    for (int i = t; i < 512; i += 256) hist[i] = 0;
    __syncthreads();

#pragma unroll
    for (int j = 0; j < CHUNK / 256; ++j) {
        int e = e0 + j * 256 + t;
        if (e < E) atomicAdd(&hist[dst[e] >> 7], 1);
    }
    __syncthreads();

    for (int b = t; b < 512; b += 256) {
        int c = hist[b];
        bbase[b] = c ? atomicAdd(&cursors[relBase + b], c) : 0;
        hist[b] = 0;    // reuse as rank counter
    }
    __syncthreads();

#pragma unroll
    for (int j = 0; j < CHUNK / 256; ++j) {
        int e = e0 + j * 256 + t;
        if (e < E) {
            int dv = dst[e];
            int bkt = dv >> 7;
            int r = atomicAdd(&hist[bkt], 1);
            stg[bbase[bkt] + r] = (src[e] & 0x1FFFF) | ((dv & 127) << 17);
        }
    }
}

// ---------------------------------------------------------------------------
// csr_fill: one block per bucket. Re-scatter the bucket's staged edges into
// exact per-node CSR order. Reads coalesced; writes random only within the
// bucket's ~6KB window (L2-resident, ~1x write amp).
// ---------------------------------------------------------------------------
__global__ __launch_bounds__(256) void csr_fill(
    const int* __restrict__ offsUU, const int* __restrict__ offsIU,
    const int* __restrict__ offsUI,
    const int* __restrict__ stgUU, const int* __restrict__ stgIU,
    const int* __restrict__ stgUI,
    int* __restrict__ srtUU, int* __restrict__ srtIU, int* __restrict__ srtUI,
    int NB0, int NB1, int NU, int NI, int E_uu, int E_iu, int E_ui)
{
    __shared__ int nodeStart[BSZ];
    __shared__ int rank[BSZ];
    __shared__ int bEnd;

    const int b = blockIdx.x;
    const int* offs; const int* stg; int* srt; int N; int Erel; int lb;
    if (b < NB0)            { lb = b;             offs = offsUU; stg = stgUU; srt = srtUU; N = NU; Erel = E_uu; }
    else if (b < NB0 + NB1) { lb = b - NB0;       offs = offsIU; stg = stgIU; srt = srtIU; N = NU; Erel = E_iu; }
    else                    { lb = b - NB0 - NB1; offs = offsUI; stg = stgUI; srt = srtUI; N = NI; Erel = E_ui; }

    const int t = threadIdx.x;
    const int node0 = lb * BSZ;
    if (t < BSZ) {
        int nd = node0 + t;
        nodeStart[t] = (nd < N) ? offs[nd] : Erel;
        rank[t] = 0;
    }
    if (t == 0) bEnd = (node0 + BSZ < N) ? offs[node0 + BSZ] : Erel;
    __syncthreads();

    const int start = nodeStart[0];
    for (int e = start + t; e < bEnd; e += 256) {
        int v = stg[e];
        int nl = (v >> 17) & 127;
        int r = atomicAdd(&rank[nl], 1);
        srt[nodeStart[nl] + r] = v & 0x1FFFF;
    }
}

// ---------------------------------------------------------------------------
// gather (fused): one wave per destination node over clean CSR; 8 source
// rows in flight (2 short8 loads per lane-group). Stores bf16 MEAN.
// ---------------------------------------------------------------------------
__global__ __launch_bounds__(256) void gather_all(
    const unsigned short* __restrict__ hbU, const unsigned short* __restrict__ hbI,
    const int* __restrict__ offsUU, const int* __restrict__ srtUU,
    const int* __restrict__ offsIU, const int* __restrict__ srtIU,
    const int* __restrict__ offsUI, const int* __restrict__ srtUI,
    unsigned short* __restrict__ accUU, unsigned short* __restrict__ accIU,
    unsigned short* __restrict__ accUI,
    int NU, int NI, int E_uu, int E_iu, int E_ui)
{
    int w = (blockIdx.x * 256 + threadIdx.x) >> 6;
    const int lane = threadIdx.x & 63;

    const unsigned short* hb; const int* offs; const int* sorted;
    unsigned short* acc; int N; int Erel;
    if (w < NU)            { hb = hbU; offs = offsUU; sorted = srtUU; acc = accUU; N = NU; Erel = E_uu; }
    else if (w < 2 * NU)   { w -= NU; hb = hbI; offs = offsIU; sorted = srtIU; acc = accIU; N = NU; Erel = E_iu; }
    else                   { w -= 2 * NU; if (w >= NI) return;
                             hb = hbU; offs = offsUI; sorted = srtUI; acc = accUI; N = NI; Erel = E_ui; }

    const int start = offs[w];
    const int end   = (w + 1 < N) ? offs[w + 1] : Erel;
    const int part  = lane & 15;
    const int slot  = lane >> 4;

    float s[8];
#pragma unroll
    for (int j = 0; j < 8; ++j) s[j] = 0.f;

    for (int base = start; base < end; base += 8) {
        const int i0 = base + slot;
        const int i1 = base + 4 + slot;
        const bool p0 = i0 < end, p1 = i1 < end;
        int s0 = 0, s1 = 0;
        if (p0) s0 = sorted[i0];
        if (p1) s1 = sorted[i1];
        short8 v0, v1;
        if (p0) v0 = *reinterpret_cast<const short8*>(hb + (size_t)s0 * D + part * 8);
        if (p1) v1 = *reinterpret_cast<const short8*>(hb + (size_t)s1 * D + part * 8);
        if (p0) {
#pragma unroll
            for (int j = 0; j < 8; ++j) s[j] += b2f((unsigned short)v0[j]);
        }
        if (p1) {
#pragma unroll
            for (int j = 0; j < 8; ++j) s[j] += b2f((unsigned short)v1[j]);
        }
    }
#pragma unroll
    for (int j = 0; j < 8; ++j) {
        s[j] += __shfl_xor(s[j], 16);
        s[j] += __shfl_xor(s[j], 32);
    }
    if (slot == 0) {
        const float scale = 1.0f / fmaxf((float)(end - start), 1.0f);
        short8 o;
#pragma unroll
        for (int j = 0; j < 8; ++j) o[j] = (short)f2b(s[j] * scale);
        *reinterpret_cast<short8*>(acc + (size_t)w * D + part * 8) = o;
    }
}

// ---------------------------------------------------------------------------
// GEMM (fused): both output types in one launch, branch on block range.
// out[N,128] = A0@W0 + A1@W1 [+ A2@W2] + bias; W* fragment-linear bf16.
// ---------------------------------------------------------------------------
__global__ __launch_bounds__(512) void gemm_all(
    const unsigned short* __restrict__ hbU,
    const unsigned short* __restrict__ accUU, const unsigned short* __restrict__ accIU,
    const short8* __restrict__ WfU0, const short8* __restrict__ WfU1,
    const short8* __restrict__ WfU2, const float* __restrict__ bsum,
    const unsigned short* __restrict__ hbI, const unsigned short* __restrict__ accUI,
    const short8* __restrict__ WfI0, const short8* __restrict__ WfI1,
    const float* __restrict__ b_ui,
    float* __restrict__ outU, float* __restrict__ outI,
    int NU, int NI, int nBlkU)
{
    __shared__ short8 lds[2048];     // 32 KB: one fragment-linear W
    const int t = threadIdx.x;
    const int w = t >> 6, l = t & 63;

    const unsigned short *A0, *A1, *A2;
    const short8 *W0, *W1, *W2;
    const float* bias; float* out; int N; int blk;
    if (blockIdx.x < nBlkU) {
        blk = blockIdx.x;
        A0 = hbU; A1 = accUU; A2 = accIU;
        W0 = WfU0; W1 = WfU1; W2 = WfU2;
        bias = bsum; out = outU; N = NU;
    } else {
        blk = blockIdx.x - nBlkU;
        A0 = hbI; A1 = accUI; A2 = nullptr;
        W0 = WfI0; W1 = WfI1; W2 = nullptr;
        bias = b_ui; out = outI; N = NI;
    }

    const int row0 = blk * 128 + w * 16;
    const int arow = row0 + (l & 15);

    f32x4 acc[8];
#pragma unroll
    for (int c = 0; c < 8; ++c) acc[c] = (f32x4){0.f, 0.f, 0.f, 0.f};

    const unsigned short* As[3] = {A0, A1, A2};
    const short8* Wfs[3] = {W0, W1, W2};
    const int nsrc = (A2 != nullptr) ? 3 : 2;

    for (int sI = 0; sI < nsrc; ++sI) {
        __syncthreads();
        const short8* Wg = Wfs[sI];
#pragma unroll
        for (int i = 0; i < 4; ++i) lds[t + i * 512] = Wg[t + i * 512];
        __syncthreads();

        const unsigned short* A = As[sI];
        short8 af[4];
        if (arow < N) {
            const unsigned short* base = A + (size_t)arow * D + ((l >> 4) << 3);
#pragma unroll
            for (int kc = 0; kc < 4; ++kc)
                af[kc] = *reinterpret_cast<const short8*>(base + kc * 32);
        } else {
            short8 z = {0, 0, 0, 0, 0, 0, 0, 0};
#pragma unroll
            for (int kc = 0; kc < 4; ++kc) af[kc] = z;
        }
#pragma unroll
        for (int kc = 0; kc < 4; ++kc)
#pragma unroll
            for (int c = 0; c < 8; ++c)
                acc[c] = __builtin_amdgcn_mfma_f32_16x16x32_bf16(
                    af[kc], lds[(c * 4 + kc) * 64 + l], acc[c], 0, 0, 0);
    }

    const int col = l & 15;
#pragma unroll
    for (int c = 0; c < 8; ++c) {
        float bv = bias[c * 16 + col];
#pragma unroll
        for (int r = 0; r < 4; ++r) {
            int row = row0 + ((l >> 4) << 2) + r;
            if (row < N)
                out[(size_t)row * D + c * 16 + col] = acc[c][r] + bv;
        }
    }
}

// ---------------------------------------------------------------------------
extern "C" void kernel_launch(void* const* d_in, const int* in_sizes, int n_in,
                              void* d_out, int out_size, void* d_ws, size_t ws_size,
                              hipStream_t stream)
{
    const float* h_user    = (const float*)d_in[0];
    const float* h_item    = (const float*)d_in[1];
    const float* Wself_uu  = (const float*)d_in[2];
    const float* Wneigh_uu = (const float*)d_in[3];
    const float* b_uu      = (const float*)d_in[4];
    const float* Wself_ui  = (const float*)d_in[5];
    const float* Wneigh_ui = (const float*)d_in[6];
    const float* b_ui      = (const float*)d_in[7];
    const float* Wself_iu  = (const float*)d_in[8];
    const float* Wneigh_iu = (const float*)d_in[9];
    const float* b_iu      = (const float*)d_in[10];
    const int* e_uu_src    = (const int*)d_in[11];
    const int* e_uu_dst    = (const int*)d_in[12];
    const int* e_ui_src    = (const int*)d_in[13];
    const int* e_ui_dst    = (const int*)d_in[14];
    const int* e_iu_src    = (const int*)d_in[15];
    const int* e_iu_dst    = (const int*)d_in[16];

    const int NU = in_sizes[0] / D;
    const int NI = in_sizes[1] / D;
    const int E_uu = in_sizes[11];
    const int E_ui = in_sizes[13];
    const int E_iu = in_sizes[15];
    const int ET = E_uu + E_iu + E_ui;

    const int NB0 = (NU + BSZ - 1) / BSZ;   // uu (dst=user)
    const int NB1 = (NU + BSZ - 1) / BSZ;   // iu (dst=user)
    const int NB2 = (NI + BSZ - 1) / BSZ;   // ui (dst=item)
    const int NBT = NB0 + NB1 + NB2;

    // ---- workspace carve-up (16B-aligned chunks) ----
    char* p = (char*)d_ws;
    unsigned short* hbU   = (unsigned short*)p; p += (size_t)NU * D * 2;
    unsigned short* hbI   = (unsigned short*)p; p += (size_t)NI * D * 2;
    unsigned short* accUU = (unsigned short*)p; p += (size_t)NU * D * 2;
    unsigned short* accIU = (unsigned short*)p; p += (size_t)NU * D * 2;
    unsigned short* accUI = (unsigned short*)p; p += (size_t)NI * D * 2;
    short8* WfU0 = (short8*)p; p += 32768;
    short8* WfU1 = (short8*)p; p += 32768;
    short8* WfU2 = (short8*)p; p += 32768;
    short8* WfI0 = (short8*)p; p += 32768;
    short8* WfI1 = (short8*)p; p += 32768;
    float* bsum  = (float*)p;  p += 512;
    int* degUU = (int*)p; p += (size_t)NU * 4;    // becomes offsUU after scan
    int* degIU = (int*)p; p += (size_t)NU * 4;    // becomes offsIU
    int* degUI = (int*)p; p += (size_t)NI * 4;    // becomes offsUI
    int* partials = (int*)p; p += 192 * 4;
    int* cursors  = (int*)p; p += (size_t)((NBT + 3) & ~3) * 4;
    int* stgUU = (int*)p; p += (size_t)E_uu * 4;
    int* stgIU = (int*)p; p += (size_t)E_iu * 4;
    int* stgUI = (int*)p; p += (size_t)E_ui * 4;
    int* srtUU = (int*)p; p += (size_t)E_uu * 4;
    int* srtIU = (int*)p; p += (size_t)E_iu * 4;
    int* srtUI = (int*)p; p += (size_t)E_ui * 4;

    // zero the node-degree counters only
    hipMemsetAsync(degUU, 0, (size_t)(2 * NU + NI) * sizeof(int), stream);

    const int nU8 = NU * D / 8, nI8 = NI * D / 8;
    const int nConvH = (nU8 + nI8 + 255) / 256;
    const int nHist  = (ET + 1023) / 1024;

    phase1<<<nConvH + 41 + nHist, 256, 0, stream>>>(
        h_user, h_item, nU8, nI8, hbU, hbI,
        Wself_uu, Wself_iu, Wneigh_uu, Wneigh_iu, Wself_ui, Wneigh_ui,
        WfU0, WfU1, WfU2, WfI0, WfI1,
        b_uu, b_iu, bsum,
        e_uu_dst, E_uu, e_iu_dst, E_iu, e_ui_dst, E_ui,
        degUU, degIU, degUI, nConvH);

    scanA_kernel<<<192, 256, 0, stream>>>(degUU, NU, degIU, NU, degUI, NI, partials);
    scanB_kernel<<<1, 192, 0, stream>>>(partials);
    scanC_kernel<<<192, 256, 0, stream>>>(degUU, NU, degIU, NU, degUI, NI,
                                          partials, cursors, NB0, NB1);

    const int nblk0 = (E_uu + CHUNK - 1) / CHUNK;
    const int nblk1 = (E_iu + CHUNK - 1) / CHUNK;
    const int nblk2 = (E_ui + CHUNK - 1) / CHUNK;
    bucket_scatter<<<nblk0 + nblk1 + nblk2, 256, 0, stream>>>(
        e_uu_src, e_uu_dst, E_uu,
        e_iu_src, e_iu_dst, E_iu,
        e_ui_src, e_ui_dst, E_ui,
        NB0, NB1, cursors, stgUU, stgIU, stgUI, nblk0, nblk1);

    csr_fill<<<NBT, 256, 0, stream>>>(
        degUU, degIU, degUI, stgUU, stgIU, stgUI,
        srtUU, srtIU, srtUI, NB0, NB1, NU, NI, E_uu, E_iu, E_ui);

    gather_all<<<(2 * NU + NI + 3) / 4, 256, 0, stream>>>(
        hbU, hbI, degUU, srtUU, degIU, srtIU, degUI, srtUI,
        accUU, accIU, accUI, NU, NI, E_uu, E_iu, E_ui);

    float* out_user = (float*)d_out;
    float* out_item = out_user + (size_t)NU * D;
    const int nBlkU = (NU + 127) / 128, nBlkI = (NI + 127) / 128;

    gemm_all<<<nBlkU + nBlkI, 512, 0, stream>>>(
        hbU, accUU, accIU, WfU0, WfU1, WfU2, bsum,
        hbI, accUI, WfI0, WfI1, b_ui,
        out_user, out_item, NU, NI, nBlkU);
}

// Round 7
// 202.451 us; speedup vs baseline: 2.3768x; 1.2348x over previous
//
#include <hip/hip_runtime.h>

#define D 128
#define BSZ 128            // dst nodes per bucket
#define CHUNK 8192         // edges per bucket_scatter block
#define CCH 16384          // edges per bucket-count chunk (phase1)

typedef __attribute__((ext_vector_type(8))) short short8;
typedef __attribute__((ext_vector_type(4))) float f32x4;

__device__ inline float b2f(unsigned short u) {
    union { unsigned int u; float f; } x; x.u = ((unsigned int)u) << 16; return x.f;
}
__device__ inline unsigned short f2b(float f) {
    union { float f; unsigned int u; } x; x.f = f;
    unsigned int r = x.u + 0x7FFFu + ((x.u >> 16) & 1u);
    return (unsigned short)(r >> 16);
}

// ---------------------------------------------------------------------------
// phase1 (fused): h fp32->bf16 conversion | W fragment packing | bias sum |
// per-bucket edge counts (LDS-privatized histogram -> ~43K global atomics).
// ---------------------------------------------------------------------------
__global__ __launch_bounds__(256) void phase1(
    const float* __restrict__ hU, const float* __restrict__ hI,
    int nU8, int nI8,
    unsigned short* __restrict__ hbU, unsigned short* __restrict__ hbI,
    const float* __restrict__ Wself_uu, const float* __restrict__ Wself_iu,
    const float* __restrict__ Wneigh_uu, const float* __restrict__ Wneigh_iu,
    const float* __restrict__ Wself_ui, const float* __restrict__ Wneigh_ui,
    short8* __restrict__ WfU0, short8* __restrict__ WfU1, short8* __restrict__ WfU2,
    short8* __restrict__ WfI0, short8* __restrict__ WfI1,
    const float* __restrict__ b_uu, const float* __restrict__ b_iu,
    float* __restrict__ bsum,
    const int* __restrict__ d_uu, int E_uu,
    const int* __restrict__ d_iu, int E_iu,
    const int* __restrict__ d_ui, int E_ui,
    int* __restrict__ counts, int NB0, int NB1,
    int nConvH, int nCnt0, int nCnt1)
{
    __shared__ int hcnt[512];
    const int b = blockIdx.x;
    const int t = threadIdx.x;

    if (b < nConvH) {
        int g = b * 256 + t;
        const float* src; unsigned short* dst;
        if (g < nU8) { src = hU + (size_t)g * 8; dst = hbU + (size_t)g * 8; }
        else {
            g -= nU8;
            if (g >= nI8) return;
            src = hI + (size_t)g * 8; dst = hbI + (size_t)g * 8;
        }
        const float4 a = *reinterpret_cast<const float4*>(src);
        const float4 c = *reinterpret_cast<const float4*>(src + 4);
        short8 o;
        o[0] = (short)f2b(a.x); o[1] = (short)f2b(a.y);
        o[2] = (short)f2b(a.z); o[3] = (short)f2b(a.w);
        o[4] = (short)f2b(c.x); o[5] = (short)f2b(c.y);
        o[6] = (short)f2b(c.z); o[7] = (short)f2b(c.w);
        *reinterpret_cast<short8*>(dst) = o;
        return;
    }
    const int wb = b - nConvH;
    if (wb < 40) {
        const float* Wa; const float* Wb = nullptr; short8* Wf;
        switch (wb >> 3) {
            case 0: Wa = Wself_uu; Wb = Wself_iu; Wf = WfU0; break;
            case 1: Wa = Wneigh_uu; Wf = WfU1; break;
            case 2: Wa = Wneigh_iu; Wf = WfU2; break;
            case 3: Wa = Wself_ui;  Wf = WfI0; break;
            default: Wa = Wneigh_ui; Wf = WfI1; break;
        }
        int t2 = (wb & 7) * 256 + t;            // 0..2047
        int c  = t2 >> 8;
        int kc = (t2 >> 6) & 3;
        int l  = t2 & 63;
        int n  = c * 16 + (l & 15);
        int k0 = kc * 32 + ((l >> 4) << 3);
        short8 o;
#pragma unroll
        for (int j = 0; j < 8; ++j) {
            float v = Wa[(k0 + j) * D + n];
            if (Wb) v += Wb[(k0 + j) * D + n];
            o[j] = (short)f2b(v);
        }
        Wf[t2] = o;
        return;
    }
    if (wb == 40) {
        if (t < D) bsum[t] = b_uu[t] + b_iu[t];
        return;
    }
    // ---- per-bucket counts: LDS histogram over one relation chunk ----
    int cb = wb - 41;
    const int* dstp; int E; int relBase; int c0;
    if (cb < nCnt0)              { dstp = d_uu; E = E_uu; relBase = 0;          c0 = cb; }
    else if (cb < nCnt0 + nCnt1) { dstp = d_iu; E = E_iu; relBase = NB0;        c0 = cb - nCnt0; }
    else                         { dstp = d_ui; E = E_ui; relBase = NB0 + NB1;  c0 = cb - nCnt0 - nCnt1; }

    for (int i = t; i < 512; i += 256) hcnt[i] = 0;
    __syncthreads();
    const int e0 = c0 * CCH;
#pragma unroll 4
    for (int j = 0; j < CCH / 256; ++j) {
        int e = e0 + j * 256 + t;
        if (e < E) atomicAdd(&hcnt[dstp[e] >> 7], 1);
    }
    __syncthreads();
    for (int i = t; i < 512; i += 256) {
        int c = hcnt[i];
        if (c) atomicAdd(&counts[relBase + i], c);
    }
}

// ---------------------------------------------------------------------------
// scan: exclusive scan of counts[NBT] -> bb[NBT+1]; cursors = copy of bases.
// Single block, 1024 threads, 2 values/thread (NBT <= 2048).
// ---------------------------------------------------------------------------
__global__ __launch_bounds__(1024) void scan_kernel(
    const int* __restrict__ counts, int NBT,
    int* __restrict__ bb, int* __restrict__ cur)
{
    __shared__ int s[1024];
    int t = threadIdx.x;
    int i0 = t * 2, i1 = t * 2 + 1;
    int v0 = (i0 < NBT) ? counts[i0] : 0;
    int v1 = (i1 < NBT) ? counts[i1] : 0;
    int sum = v0 + v1;
    s[t] = sum;
    __syncthreads();
    for (int off = 1; off < 1024; off <<= 1) {
        int x = (t >= off) ? s[t - off] : 0;
        __syncthreads();
        s[t] += x;
        __syncthreads();
    }
    int pre = s[t] - sum;   // exclusive prefix
    if (i0 < NBT) { bb[i0] = pre;      cur[i0] = pre; }
    if (i1 < NBT) { bb[i1] = pre + v0; cur[i1] = pre + v0; }
    if (t == 1023) bb[NBT] = s[1023];
}

// ---------------------------------------------------------------------------
// bucket_scatter: group edges by 128-dst bucket into ONE concatenated
// staging buffer (packed int: src | dstLocal<<17) at global bucket windows.
// Block-aggregated reservation -> semi-coalesced runs, no write blow-up.
// ---------------------------------------------------------------------------
__global__ __launch_bounds__(256) void bucket_scatter(
    const int* __restrict__ s_uu, const int* __restrict__ d_uu, int E_uu,
    const int* __restrict__ s_iu, const int* __restrict__ d_iu, int E_iu,
    const int* __restrict__ s_ui, const int* __restrict__ d_ui, int E_ui,
    int NB0, int NB1,
    int* __restrict__ cursors, int* __restrict__ stg,
    int nblk0, int nblk1)
{
    __shared__ int hist[512];
    __shared__ int bbase[512];

    const int* src; const int* dst; int E; int relBase; int b0;
    if (blockIdx.x < nblk0) {
        b0 = blockIdx.x; src = s_uu; dst = d_uu; E = E_uu; relBase = 0;
    } else if (blockIdx.x < nblk0 + nblk1) {
        b0 = blockIdx.x - nblk0; src = s_iu; dst = d_iu; E = E_iu; relBase = NB0;
    } else {
        b0 = blockIdx.x - nblk0 - nblk1; src = s_ui; dst = d_ui; E = E_ui;
        relBase = NB0 + NB1;
    }
    const int t = threadIdx.x;
    const int e0 = b0 * CHUNK;

    for (int i = t; i < 512; i += 256) hist[i] = 0;
    __syncthreads();

#pragma unroll
    for (int j = 0; j < CHUNK / 256; ++j) {
        int e = e0 + j * 256 + t;
        if (e < E) atomicAdd(&hist[dst[e] >> 7], 1);
    }
    __syncthreads();

    for (int b = t; b < 512; b += 256) {
        int c = hist[b];
        bbase[b] = c ? atomicAdd(&cursors[relBase + b], c) : 0;
        hist[b] = 0;    // reuse as rank counter
    }
    __syncthreads();

#pragma unroll
    for (int j = 0; j < CHUNK / 256; ++j) {
        int e = e0 + j * 256 + t;
        if (e < E) {
            int dv = dst[e];
            int bkt = dv >> 7;
            int r = atomicAdd(&hist[bkt], 1);
            stg[bbase[bkt] + r] = (src[e] & 0x1FFFF) | ((dv & 127) << 17);
        }
    }
}

// ---------------------------------------------------------------------------
// csr_fill: one block per bucket. From the staged window, compute per-node
// degree + global CSR start (LDS count + LDS scan), then re-scatter into
// exact CSR order. All node-granularity atomics are LDS-speed.
// ---------------------------------------------------------------------------
__global__ __launch_bounds__(256) void csr_fill(
    const int* __restrict__ stg, const int* __restrict__ bb,
    int* __restrict__ srt,
    int* __restrict__ offsUU, int* __restrict__ degUU,
    int* __restrict__ offsIU, int* __restrict__ degIU,
    int* __restrict__ offsUI, int* __restrict__ degUI,
    int NB0, int NB1, int NU, int NI)
{
    __shared__ int cnt[BSZ];
    __shared__ int st[BSZ];
    __shared__ int rank[BSZ];
    __shared__ int sc[BSZ];

    const int b = blockIdx.x;
    int* offs; int* deg; int N; int lb;
    if (b < NB0)            { lb = b;             offs = offsUU; deg = degUU; N = NU; }
    else if (b < NB0 + NB1) { lb = b - NB0;       offs = offsIU; deg = degIU; N = NU; }
    else                    { lb = b - NB0 - NB1; offs = offsUI; deg = degUI; N = NI; }

    const int t = threadIdx.x;
    const int node0 = lb * BSZ;
    const int bLo = bb[b], bHi = bb[b + 1];

    if (t < BSZ) { cnt[t] = 0; rank[t] = 0; }
    __syncthreads();

    for (int e = bLo + t; e < bHi; e += 256)
        atomicAdd(&cnt[(stg[e] >> 17) & 127], 1);
    __syncthreads();

    // exclusive scan of cnt[128] (Hillis-Steele, all threads hit syncs)
    if (t < BSZ) sc[t] = cnt[t];
    __syncthreads();
    for (int off = 1; off < BSZ; off <<= 1) {
        int x = 0;
        if (t < BSZ && t >= off) x = sc[t - off];
        __syncthreads();
        if (t < BSZ) sc[t] += x;
        __syncthreads();
    }
    if (t < BSZ) {
        st[t] = sc[t] - cnt[t];
        int node = node0 + t;
        if (node < N) {
            deg[node]  = cnt[t];
            offs[node] = bLo + st[t];
        }
    }
    __syncthreads();

    for (int e = bLo + t; e < bHi; e += 256) {
        int v = stg[e];
        int nl = (v >> 17) & 127;
        int r = atomicAdd(&rank[nl], 1);
        srt[bLo + st[nl] + r] = v & 0x1FFFF;
    }
}

// ---------------------------------------------------------------------------
// gather (fused): one wave per destination node over clean CSR; 8 source
// rows in flight. Stores bf16 MEAN. start/end from offs/deg (global srt).
// ---------------------------------------------------------------------------
__global__ __launch_bounds__(256) void gather_all(
    const unsigned short* __restrict__ hbU, const unsigned short* __restrict__ hbI,
    const int* __restrict__ srt,
    const int* __restrict__ offsUU, const int* __restrict__ degUU,
    const int* __restrict__ offsIU, const int* __restrict__ degIU,
    const int* __restrict__ offsUI, const int* __restrict__ degUI,
    unsigned short* __restrict__ accUU, unsigned short* __restrict__ accIU,
    unsigned short* __restrict__ accUI,
    int NU, int NI)
{
    int w = (blockIdx.x * 256 + threadIdx.x) >> 6;
    const int lane = threadIdx.x & 63;

    const unsigned short* hb; const int* offs; const int* deg;
    unsigned short* acc;
    if (w < NU)            { hb = hbU; offs = offsUU; deg = degUU; acc = accUU; }
    else if (w < 2 * NU)   { w -= NU; hb = hbI; offs = offsIU; deg = degIU; acc = accIU; }
    else                   { w -= 2 * NU; if (w >= NI) return;
                             hb = hbU; offs = offsUI; deg = degUI; acc = accUI; }

    const int start = offs[w];
    const int dg    = deg[w];
    const int end   = start + dg;
    const int part  = lane & 15;
    const int slot  = lane >> 4;

    float s[8];
#pragma unroll
    for (int j = 0; j < 8; ++j) s[j] = 0.f;

    for (int base = start; base < end; base += 8) {
        const int i0 = base + slot;
        const int i1 = base + 4 + slot;
        const bool p0 = i0 < end, p1 = i1 < end;
        int s0 = 0, s1 = 0;
        if (p0) s0 = srt[i0];
        if (p1) s1 = srt[i1];
        short8 v0, v1;
        if (p0) v0 = *reinterpret_cast<const short8*>(hb + (size_t)s0 * D + part * 8);
        if (p1) v1 = *reinterpret_cast<const short8*>(hb + (size_t)s1 * D + part * 8);
        if (p0) {
#pragma unroll
            for (int j = 0; j < 8; ++j) s[j] += b2f((unsigned short)v0[j]);
        }
        if (p1) {
#pragma unroll
            for (int j = 0; j < 8; ++j) s[j] += b2f((unsigned short)v1[j]);
        }
    }
#pragma unroll
    for (int j = 0; j < 8; ++j) {
        s[j] += __shfl_xor(s[j], 16);
        s[j] += __shfl_xor(s[j], 32);
    }
    if (slot == 0) {
        const float scale = 1.0f / fmaxf((float)dg, 1.0f);
        short8 o;
#pragma unroll
        for (int j = 0; j < 8; ++j) o[j] = (short)f2b(s[j] * scale);
        *reinterpret_cast<short8*>(acc + (size_t)w * D + part * 8) = o;
    }
}

// ---------------------------------------------------------------------------
// GEMM (fused): both output types in one launch, branch on block range.
// out[N,128] = A0@W0 + A1@W1 [+ A2@W2] + bias; W* fragment-linear bf16.
// ---------------------------------------------------------------------------
__global__ __launch_bounds__(512) void gemm_all(
    const unsigned short* __restrict__ hbU,
    const unsigned short* __restrict__ accUU, const unsigned short* __restrict__ accIU,
    const short8* __restrict__ WfU0, const short8* __restrict__ WfU1,
    const short8* __restrict__ WfU2, const float* __restrict__ bsum,
    const unsigned short* __restrict__ hbI, const unsigned short* __restrict__ accUI,
    const short8* __restrict__ WfI0, const short8* __restrict__ WfI1,
    const float* __restrict__ b_ui,
    float* __restrict__ outU, float* __restrict__ outI,
    int NU, int NI, int nBlkU)
{
    __shared__ short8 lds[2048];     // 32 KB: one fragment-linear W
    const int t = threadIdx.x;
    const int w = t >> 6, l = t & 63;

    const unsigned short *A0, *A1, *A2;
    const short8 *W0, *W1, *W2;
    const float* bias; float* out; int N; int blk;
    if (blockIdx.x < nBlkU) {
        blk = blockIdx.x;
        A0 = hbU; A1 = accUU; A2 = accIU;
        W0 = WfU0; W1 = WfU1; W2 = WfU2;
        bias = bsum; out = outU; N = NU;
    } else {
        blk = blockIdx.x - nBlkU;
        A0 = hbI; A1 = accUI; A2 = nullptr;
        W0 = WfI0; W1 = WfI1; W2 = nullptr;
        bias = b_ui; out = outI; N = NI;
    }

    const int row0 = blk * 128 + w * 16;
    const int arow = row0 + (l & 15);

    f32x4 acc[8];
#pragma unroll
    for (int c = 0; c < 8; ++c) acc[c] = (f32x4){0.f, 0.f, 0.f, 0.f};

    const unsigned short* As[3] = {A0, A1, A2};
    const short8* Wfs[3] = {W0, W1, W2};
    const int nsrc = (A2 != nullptr) ? 3 : 2;

    for (int sI = 0; sI < nsrc; ++sI) {
        __syncthreads();
        const short8* Wg = Wfs[sI];
#pragma unroll
        for (int i = 0; i < 4; ++i) lds[t + i * 512] = Wg[t + i * 512];
        __syncthreads();

        const unsigned short* A = As[sI];
        short8 af[4];
        if (arow < N) {
            const unsigned short* base = A + (size_t)arow * D + ((l >> 4) << 3);
#pragma unroll
            for (int kc = 0; kc < 4; ++kc)
                af[kc] = *reinterpret_cast<const short8*>(base + kc * 32);
        } else {
            short8 z = {0, 0, 0, 0, 0, 0, 0, 0};
#pragma unroll
            for (int kc = 0; kc < 4; ++kc) af[kc] = z;
        }
#pragma unroll
        for (int kc = 0; kc < 4; ++kc)
#pragma unroll
            for (int c = 0; c < 8; ++c)
                acc[c] = __builtin_amdgcn_mfma_f32_16x16x32_bf16(
                    af[kc], lds[(c * 4 + kc) * 64 + l], acc[c], 0, 0, 0);
    }

    const int col = l & 15;
#pragma unroll
    for (int c = 0; c < 8; ++c) {
        float bv = bias[c * 16 + col];
#pragma unroll
        for (int r = 0; r < 4; ++r) {
            int row = row0 + ((l >> 4) << 2) + r;
            if (row < N)
                out[(size_t)row * D + c * 16 + col] = acc[c][r] + bv;
        }
    }
}

// ---------------------------------------------------------------------------
extern "C" void kernel_launch(void* const* d_in, const int* in_sizes, int n_in,
                              void* d_out, int out_size, void* d_ws, size_t ws_size,
                              hipStream_t stream)
{
    const float* h_user    = (const float*)d_in[0];
    const float* h_item    = (const float*)d_in[1];
    const float* Wself_uu  = (const float*)d_in[2];
    const float* Wneigh_uu = (const float*)d_in[3];
    const float* b_uu      = (const float*)d_in[4];
    const float* Wself_ui  = (const float*)d_in[5];
    const float* Wneigh_ui = (const float*)d_in[6];
    const float* b_ui      = (const float*)d_in[7];
    const float* Wself_iu  = (const float*)d_in[8];
    const float* Wneigh_iu = (const float*)d_in[9];
    const float* b_iu      = (const float*)d_in[10];
    const int* e_uu_src    = (const int*)d_in[11];
    const int* e_uu_dst    = (const int*)d_in[12];
    const int* e_ui_src    = (const int*)d_in[13];
    const int* e_ui_dst    = (const int*)d_in[14];
    const int* e_iu_src    = (const int*)d_in[15];
    const int* e_iu_dst    = (const int*)d_in[16];

    const int NU = in_sizes[0] / D;
    const int NI = in_sizes[1] / D;
    const int E_uu = in_sizes[11];
    const int E_ui = in_sizes[13];
    const int E_iu = in_sizes[15];
    const int ET = E_uu + E_iu + E_ui;

    const int NB0 = (NU + BSZ - 1) / BSZ;   // uu (dst=user)
    const int NB1 = (NU + BSZ - 1) / BSZ;   // iu (dst=user)
    const int NB2 = (NI + BSZ - 1) / BSZ;   // ui (dst=item)
    const int NBT = NB0 + NB1 + NB2;

    // ---- workspace carve-up (16B-aligned chunks) ----
    char* p = (char*)d_ws;
    unsigned short* hbU   = (unsigned short*)p; p += (size_t)NU * D * 2;
    unsigned short* hbI   = (unsigned short*)p; p += (size_t)NI * D * 2;
    unsigned short* accUU = (unsigned short*)p; p += (size_t)NU * D * 2;
    unsigned short* accIU = (unsigned short*)p; p += (size_t)NU * D * 2;
    unsigned short* accUI = (unsigned short*)p; p += (size_t)NI * D * 2;
    short8* WfU0 = (short8*)p; p += 32768;
    short8* WfU1 = (short8*)p; p += 32768;
    short8* WfU2 = (short8*)p; p += 32768;
    short8* WfI0 = (short8*)p; p += 32768;
    short8* WfI1 = (short8*)p; p += 32768;
    float* bsum  = (float*)p;  p += 512;
    int* counts  = (int*)p; p += (size_t)((NBT + 3) & ~3) * 4;
    int* bb      = (int*)p; p += (size_t)((NBT + 4) & ~3) * 4;
    int* cursors = (int*)p; p += (size_t)((NBT + 3) & ~3) * 4;
    int* offsUU  = (int*)p; p += (size_t)NU * 4;
    int* degUU_  = (int*)p; p += (size_t)NU * 4;
    int* offsIU  = (int*)p; p += (size_t)NU * 4;
    int* degIU_  = (int*)p; p += (size_t)NU * 4;
    int* offsUI  = (int*)p; p += (size_t)NI * 4;
    int* degUI_  = (int*)p; p += (size_t)NI * 4;
    int* stg     = (int*)p; p += (size_t)ET * 4;
    int* srt     = (int*)p; p += (size_t)ET * 4;

    // zero only the bucket counters (4.7 KB)
    hipMemsetAsync(counts, 0, (size_t)NBT * sizeof(int), stream);

    const int nU8 = NU * D / 8, nI8 = NI * D / 8;
    const int nConvH = (nU8 + nI8 + 255) / 256;
    const int nCnt0 = (E_uu + CCH - 1) / CCH;
    const int nCnt1 = (E_iu + CCH - 1) / CCH;
    const int nCnt2 = (E_ui + CCH - 1) / CCH;

    phase1<<<nConvH + 41 + nCnt0 + nCnt1 + nCnt2, 256, 0, stream>>>(
        h_user, h_item, nU8, nI8, hbU, hbI,
        Wself_uu, Wself_iu, Wneigh_uu, Wneigh_iu, Wself_ui, Wneigh_ui,
        WfU0, WfU1, WfU2, WfI0, WfI1,
        b_uu, b_iu, bsum,
        e_uu_dst, E_uu, e_iu_dst, E_iu, e_ui_dst, E_ui,
        counts, NB0, NB1, nConvH, nCnt0, nCnt1);

    scan_kernel<<<1, 1024, 0, stream>>>(counts, NBT, bb, cursors);

    const int nblk0 = (E_uu + CHUNK - 1) / CHUNK;
    const int nblk1 = (E_iu + CHUNK - 1) / CHUNK;
    const int nblk2 = (E_ui + CHUNK - 1) / CHUNK;
    bucket_scatter<<<nblk0 + nblk1 + nblk2, 256, 0, stream>>>(
        e_uu_src, e_uu_dst, E_uu,
        e_iu_src, e_iu_dst, E_iu,
        e_ui_src, e_ui_dst, E_ui,
        NB0, NB1, cursors, stg, nblk0, nblk1);

    csr_fill<<<NBT, 256, 0, stream>>>(
        stg, bb, srt,
        offsUU, degUU_, offsIU, degIU_, offsUI, degUI_,
        NB0, NB1, NU, NI);

    gather_all<<<(2 * NU + NI + 3) / 4, 256, 0, stream>>>(
        hbU, hbI, srt,
        offsUU, degUU_, offsIU, degIU_, offsUI, degUI_,
        accUU, accIU, accUI, NU, NI);

    float* out_user = (float*)d_out;
    float* out_item = out_user + (size_t)NU * D;
    const int nBlkU = (NU + 127) / 128, nBlkI = (NI + 127) / 128;

    gemm_all<<<nBlkU + nBlkI, 512, 0, stream>>>(
        hbU, accUU, accIU, WfU0, WfU1, WfU2, bsum,
        hbI, accUI, WfI0, WfI1, b_ui,
        out_user, out_item, NU, NI, nBlkU);
}

// Round 8
// 181.010 us; speedup vs baseline: 2.6583x; 1.1184x over previous
//
#include <hip/hip_runtime.h>

#define D 128
#define BSZ 128            // dst nodes per bucket
#define CHUNK 8192         // edges per bucket_scatter block
#define CCH 16384          // edges per hist chunk

typedef __attribute__((ext_vector_type(8))) short short8;
typedef __attribute__((ext_vector_type(4))) float f32x4;

__device__ inline float b2f(unsigned short u) {
    union { unsigned int u; float f; } x; x.u = ((unsigned int)u) << 16; return x.f;
}
__device__ inline unsigned short f2b(float f) {
    union { float f; unsigned int u; } x; x.f = f;
    unsigned int r = x.u + 0x7FFFu + ((x.u >> 16) & 1u);
    return (unsigned short)(r >> 16);
}

// ---------------------------------------------------------------------------
// hist: per-bucket edge counts (LDS-privatized -> ~43K global atomics).
// ---------------------------------------------------------------------------
__global__ __launch_bounds__(256) void hist_kernel(
    const int* __restrict__ d_uu, int E_uu,
    const int* __restrict__ d_iu, int E_iu,
    const int* __restrict__ d_ui, int E_ui,
    int* __restrict__ counts, int NB0, int NB1, int nCnt0, int nCnt1)
{
    __shared__ int hcnt[512];
    const int t = threadIdx.x;
    int cb = blockIdx.x;
    const int* dstp; int E; int relBase; int c0;
    if (cb < nCnt0)              { dstp = d_uu; E = E_uu; relBase = 0;          c0 = cb; }
    else if (cb < nCnt0 + nCnt1) { dstp = d_iu; E = E_iu; relBase = NB0;        c0 = cb - nCnt0; }
    else                         { dstp = d_ui; E = E_ui; relBase = NB0 + NB1;  c0 = cb - nCnt0 - nCnt1; }

    for (int i = t; i < 512; i += 256) hcnt[i] = 0;
    __syncthreads();
    const int e0 = c0 * CCH;
#pragma unroll 4
    for (int j = 0; j < CCH / 256; ++j) {
        int e = e0 + j * 256 + t;
        if (e < E) atomicAdd(&hcnt[dstp[e] >> 7], 1);
    }
    __syncthreads();
    for (int i = t; i < 512; i += 256) {
        int c = hcnt[i];
        if (c) atomicAdd(&counts[relBase + i], c);
    }
}

// ---------------------------------------------------------------------------
// scan: exclusive scan of counts[NBT] -> bb[NBT+1]; cursors = copy of bases.
// ---------------------------------------------------------------------------
__global__ __launch_bounds__(1024) void scan_kernel(
    const int* __restrict__ counts, int NBT,
    int* __restrict__ bb, int* __restrict__ cur)
{
    __shared__ int s[1024];
    int t = threadIdx.x;
    int i0 = t * 2, i1 = t * 2 + 1;
    int v0 = (i0 < NBT) ? counts[i0] : 0;
    int v1 = (i1 < NBT) ? counts[i1] : 0;
    int sum = v0 + v1;
    s[t] = sum;
    __syncthreads();
    for (int off = 1; off < 1024; off <<= 1) {
        int x = (t >= off) ? s[t - off] : 0;
        __syncthreads();
        s[t] += x;
        __syncthreads();
    }
    int pre = s[t] - sum;   // exclusive prefix
    if (i0 < NBT) { bb[i0] = pre;      cur[i0] = pre; }
    if (i1 < NBT) { bb[i1] = pre + v0; cur[i1] = pre + v0; }
    if (t == 1023) bb[NBT] = s[1023];
}

// ---------------------------------------------------------------------------
// scatter_conv (fused): [0,nblkS) bucket scatter | rest: h fp32->bf16 conv.
// Scatter groups edges by 128-dst bucket into staged windows (packed int:
// src | dstLocal<<17) via block-aggregated reservations.
// ---------------------------------------------------------------------------
__global__ __launch_bounds__(256) void scatter_conv(
    const int* __restrict__ s_uu, const int* __restrict__ d_uu, int E_uu,
    const int* __restrict__ s_iu, const int* __restrict__ d_iu, int E_iu,
    const int* __restrict__ s_ui, const int* __restrict__ d_ui, int E_ui,
    int NB0, int NB1,
    int* __restrict__ cursors, int* __restrict__ stg,
    int nblk0, int nblk1, int nblkS,
    const float* __restrict__ hU, const float* __restrict__ hI,
    int nU8, int nI8,
    unsigned short* __restrict__ hbU, unsigned short* __restrict__ hbI)
{
    __shared__ int hist[512];
    __shared__ int bbase[512];
    const int t = threadIdx.x;

    if (blockIdx.x >= nblkS) {
        // ---- h conversion: 8 floats per thread ----
        int g = (blockIdx.x - nblkS) * 256 + t;
        const float* src; unsigned short* dst;
        if (g < nU8) { src = hU + (size_t)g * 8; dst = hbU + (size_t)g * 8; }
        else {
            g -= nU8;
            if (g >= nI8) return;
            src = hI + (size_t)g * 8; dst = hbI + (size_t)g * 8;
        }
        const float4 a = *reinterpret_cast<const float4*>(src);
        const float4 c = *reinterpret_cast<const float4*>(src + 4);
        short8 o;
        o[0] = (short)f2b(a.x); o[1] = (short)f2b(a.y);
        o[2] = (short)f2b(a.z); o[3] = (short)f2b(a.w);
        o[4] = (short)f2b(c.x); o[5] = (short)f2b(c.y);
        o[6] = (short)f2b(c.z); o[7] = (short)f2b(c.w);
        *reinterpret_cast<short8*>(dst) = o;
        return;
    }

    const int* src; const int* dst; int E; int relBase; int b0;
    if (blockIdx.x < nblk0) {
        b0 = blockIdx.x; src = s_uu; dst = d_uu; E = E_uu; relBase = 0;
    } else if (blockIdx.x < nblk0 + nblk1) {
        b0 = blockIdx.x - nblk0; src = s_iu; dst = d_iu; E = E_iu; relBase = NB0;
    } else {
        b0 = blockIdx.x - nblk0 - nblk1; src = s_ui; dst = d_ui; E = E_ui;
        relBase = NB0 + NB1;
    }
    const int e0 = b0 * CHUNK;

    for (int i = t; i < 512; i += 256) hist[i] = 0;
    __syncthreads();

#pragma unroll
    for (int j = 0; j < CHUNK / 256; ++j) {
        int e = e0 + j * 256 + t;
        if (e < E) atomicAdd(&hist[dst[e] >> 7], 1);
    }
    __syncthreads();

    for (int b = t; b < 512; b += 256) {
        int c = hist[b];
        bbase[b] = c ? atomicAdd(&cursors[relBase + b], c) : 0;
        hist[b] = 0;    // reuse as rank counter
    }
    __syncthreads();

#pragma unroll
    for (int j = 0; j < CHUNK / 256; ++j) {
        int e = e0 + j * 256 + t;
        if (e < E) {
            int dv = dst[e];
            int bkt = dv >> 7;
            int r = atomicAdd(&hist[bkt], 1);
            stg[bbase[bkt] + r] = (src[e] & 0x1FFFF) | ((dv & 127) << 17);
        }
    }
}

// ---------------------------------------------------------------------------
// fill_wpack (fused): [0,NBT) csr_fill per bucket | [NBT,NBT+40) W fragment
// packing | [NBT+40] bias sum.
// ---------------------------------------------------------------------------
__global__ __launch_bounds__(256) void fill_wpack(
    const int* __restrict__ stg, const int* __restrict__ bb,
    int* __restrict__ srt,
    int* __restrict__ offsUU, int* __restrict__ degUU,
    int* __restrict__ offsIU, int* __restrict__ degIU,
    int* __restrict__ offsUI, int* __restrict__ degUI,
    int NB0, int NB1, int NU, int NI, int NBT,
    const float* __restrict__ Wself_uu, const float* __restrict__ Wself_iu,
    const float* __restrict__ Wneigh_uu, const float* __restrict__ Wneigh_iu,
    const float* __restrict__ Wself_ui, const float* __restrict__ Wneigh_ui,
    short8* __restrict__ WfU0, short8* __restrict__ WfU1, short8* __restrict__ WfU2,
    short8* __restrict__ WfI0, short8* __restrict__ WfI1,
    const float* __restrict__ b_uu, const float* __restrict__ b_iu,
    float* __restrict__ bsum)
{
    const int t = threadIdx.x;
    if (blockIdx.x >= NBT) {
        const int wb = blockIdx.x - NBT;
        if (wb < 40) {
            const float* Wa; const float* Wb = nullptr; short8* Wf;
            switch (wb >> 3) {
                case 0: Wa = Wself_uu; Wb = Wself_iu; Wf = WfU0; break;
                case 1: Wa = Wneigh_uu; Wf = WfU1; break;
                case 2: Wa = Wneigh_iu; Wf = WfU2; break;
                case 3: Wa = Wself_ui;  Wf = WfI0; break;
                default: Wa = Wneigh_ui; Wf = WfI1; break;
            }
            int t2 = (wb & 7) * 256 + t;            // 0..2047
            int c  = t2 >> 8;
            int kc = (t2 >> 6) & 3;
            int l  = t2 & 63;
            int n  = c * 16 + (l & 15);
            int k0 = kc * 32 + ((l >> 4) << 3);
            short8 o;
#pragma unroll
            for (int j = 0; j < 8; ++j) {
                float v = Wa[(k0 + j) * D + n];
                if (Wb) v += Wb[(k0 + j) * D + n];
                o[j] = (short)f2b(v);
            }
            Wf[t2] = o;
        } else {
            if (t < D) bsum[t] = b_uu[t] + b_iu[t];
        }
        return;
    }

    __shared__ int cnt[BSZ];
    __shared__ int st[BSZ];
    __shared__ int rank[BSZ];
    __shared__ int sc[BSZ];

    const int b = blockIdx.x;
    int* offs; int* deg; int N; int lb;
    if (b < NB0)            { lb = b;             offs = offsUU; deg = degUU; N = NU; }
    else if (b < NB0 + NB1) { lb = b - NB0;       offs = offsIU; deg = degIU; N = NU; }
    else                    { lb = b - NB0 - NB1; offs = offsUI; deg = degUI; N = NI; }

    const int node0 = lb * BSZ;
    const int bLo = bb[b], bHi = bb[b + 1];

    if (t < BSZ) { cnt[t] = 0; rank[t] = 0; }
    __syncthreads();

    for (int e = bLo + t; e < bHi; e += 256)
        atomicAdd(&cnt[(stg[e] >> 17) & 127], 1);
    __syncthreads();

    if (t < BSZ) sc[t] = cnt[t];
    __syncthreads();
    for (int off = 1; off < BSZ; off <<= 1) {
        int x = 0;
        if (t < BSZ && t >= off) x = sc[t - off];
        __syncthreads();
        if (t < BSZ) sc[t] += x;
        __syncthreads();
    }
    if (t < BSZ) {
        st[t] = sc[t] - cnt[t];
        int node = node0 + t;
        if (node < N) {
            deg[node]  = cnt[t];
            offs[node] = bLo + st[t];
        }
    }
    __syncthreads();

    for (int e = bLo + t; e < bHi; e += 256) {
        int v = stg[e];
        int nl = (v >> 17) & 127;
        int r = atomicAdd(&rank[nl], 1);
        srt[bLo + st[nl] + r] = v & 0x1FFFF;
    }
}

// ---------------------------------------------------------------------------
// gather (v2): one wave per node. Main loop is predicate-free (8 rows/iter,
// 16 lanes x 16B per 256B row, 4 slot-groups); single predicated tail.
// Stores bf16 MEAN.
// ---------------------------------------------------------------------------
__global__ __launch_bounds__(256) void gather_all(
    const unsigned short* __restrict__ hbU, const unsigned short* __restrict__ hbI,
    const int* __restrict__ srt,
    const int* __restrict__ offsUU, const int* __restrict__ degUU,
    const int* __restrict__ offsIU, const int* __restrict__ degIU,
    const int* __restrict__ offsUI, const int* __restrict__ degUI,
    unsigned short* __restrict__ accUU, unsigned short* __restrict__ accIU,
    unsigned short* __restrict__ accUI,
    int NU, int NI)
{
    int w = (blockIdx.x * 256 + threadIdx.x) >> 6;
    const int lane = threadIdx.x & 63;

    const unsigned short* hb; const int* offs; const int* deg;
    unsigned short* acc;
    if (w < NU)            { hb = hbU; offs = offsUU; deg = degUU; acc = accUU; }
    else if (w < 2 * NU)   { w -= NU; hb = hbI; offs = offsIU; deg = degIU; acc = accIU; }
    else                   { w -= 2 * NU; if (w >= NI) return;
                             hb = hbU; offs = offsUI; deg = degUI; acc = accUI; }

    const int start = offs[w];
    const int dg    = deg[w];
    const int end   = start + dg;
    const int part  = lane & 15;
    const int slot  = lane >> 4;
    const unsigned short* hbp = hb + part * 8;

    float s[8];
#pragma unroll
    for (int j = 0; j < 8; ++j) s[j] = 0.f;

    int base = start;
    // main loop: no predication, 8 rows in flight
    for (; base + 8 <= end; base += 8) {
        const int s0 = srt[base + slot];
        const int s1 = srt[base + 4 + slot];
        const short8 v0 = *reinterpret_cast<const short8*>(hbp + (size_t)s0 * D);
        const short8 v1 = *reinterpret_cast<const short8*>(hbp + (size_t)s1 * D);
#pragma unroll
        for (int j = 0; j < 8; ++j) s[j] += b2f((unsigned short)v0[j]);
#pragma unroll
        for (int j = 0; j < 8; ++j) s[j] += b2f((unsigned short)v1[j]);
    }
    // tail (executed at most once)
    {
        const int i0 = base + slot;
        const int i1 = base + 4 + slot;
        if (i0 < end) {
            const int s0 = srt[i0];
            const short8 v0 = *reinterpret_cast<const short8*>(hbp + (size_t)s0 * D);
#pragma unroll
            for (int j = 0; j < 8; ++j) s[j] += b2f((unsigned short)v0[j]);
        }
        if (i1 < end) {
            const int s1 = srt[i1];
            const short8 v1 = *reinterpret_cast<const short8*>(hbp + (size_t)s1 * D);
#pragma unroll
            for (int j = 0; j < 8; ++j) s[j] += b2f((unsigned short)v1[j]);
        }
    }
#pragma unroll
    for (int j = 0; j < 8; ++j) {
        s[j] += __shfl_xor(s[j], 16);
        s[j] += __shfl_xor(s[j], 32);
    }
    if (slot == 0) {
        const float scale = 1.0f / fmaxf((float)dg, 1.0f);
        short8 o;
#pragma unroll
        for (int j = 0; j < 8; ++j) o[j] = (short)f2b(s[j] * scale);
        *reinterpret_cast<short8*>(acc + (size_t)w * D + part * 8) = o;
    }
}

// ---------------------------------------------------------------------------
// GEMM (fused): both output types in one launch, branch on block range.
// out[N,128] = A0@W0 + A1@W1 [+ A2@W2] + bias; W* fragment-linear bf16.
// ---------------------------------------------------------------------------
__global__ __launch_bounds__(512) void gemm_all(
    const unsigned short* __restrict__ hbU,
    const unsigned short* __restrict__ accUU, const unsigned short* __restrict__ accIU,
    const short8* __restrict__ WfU0, const short8* __restrict__ WfU1,
    const short8* __restrict__ WfU2, const float* __restrict__ bsum,
    const unsigned short* __restrict__ hbI, const unsigned short* __restrict__ accUI,
    const short8* __restrict__ WfI0, const short8* __restrict__ WfI1,
    const float* __restrict__ b_ui,
    float* __restrict__ outU, float* __restrict__ outI,
    int NU, int NI, int nBlkU)
{
    __shared__ short8 lds[2048];     // 32 KB: one fragment-linear W
    const int t = threadIdx.x;
    const int w = t >> 6, l = t & 63;

    const unsigned short *A0, *A1, *A2;
    const short8 *W0, *W1, *W2;
    const float* bias; float* out; int N; int blk;
    if (blockIdx.x < nBlkU) {
        blk = blockIdx.x;
        A0 = hbU; A1 = accUU; A2 = accIU;
        W0 = WfU0; W1 = WfU1; W2 = WfU2;
        bias = bsum; out = outU; N = NU;
    } else {
        blk = blockIdx.x - nBlkU;
        A0 = hbI; A1 = accUI; A2 = nullptr;
        W0 = WfI0; W1 = WfI1; W2 = nullptr;
        bias = b_ui; out = outI; N = NI;
    }

    const int row0 = blk * 128 + w * 16;
    const int arow = row0 + (l & 15);

    f32x4 acc[8];
#pragma unroll
    for (int c = 0; c < 8; ++c) acc[c] = (f32x4){0.f, 0.f, 0.f, 0.f};

    const unsigned short* As[3] = {A0, A1, A2};
    const short8* Wfs[3] = {W0, W1, W2};
    const int nsrc = (A2 != nullptr) ? 3 : 2;

    for (int sI = 0; sI < nsrc; ++sI) {
        __syncthreads();
        const short8* Wg = Wfs[sI];
#pragma unroll
        for (int i = 0; i < 4; ++i) lds[t + i * 512] = Wg[t + i * 512];
        __syncthreads();

        const unsigned short* A = As[sI];
        short8 af[4];
        if (arow < N) {
            const unsigned short* base = A + (size_t)arow * D + ((l >> 4) << 3);
#pragma unroll
            for (int kc = 0; kc < 4; ++kc)
                af[kc] = *reinterpret_cast<const short8*>(base + kc * 32);
        } else {
            short8 z = {0, 0, 0, 0, 0, 0, 0, 0};
#pragma unroll
            for (int kc = 0; kc < 4; ++kc) af[kc] = z;
        }
#pragma unroll
        for (int kc = 0; kc < 4; ++kc)
#pragma unroll
            for (int c = 0; c < 8; ++c)
                acc[c] = __builtin_amdgcn_mfma_f32_16x16x32_bf16(
                    af[kc], lds[(c * 4 + kc) * 64 + l], acc[c], 0, 0, 0);
    }

    const int col = l & 15;
#pragma unroll
    for (int c = 0; c < 8; ++c) {
        float bv = bias[c * 16 + col];
#pragma unroll
        for (int r = 0; r < 4; ++r) {
            int row = row0 + ((l >> 4) << 2) + r;
            if (row < N)
                out[(size_t)row * D + c * 16 + col] = acc[c][r] + bv;
        }
    }
}

// ---------------------------------------------------------------------------
extern "C" void kernel_launch(void* const* d_in, const int* in_sizes, int n_in,
                              void* d_out, int out_size, void* d_ws, size_t ws_size,
                              hipStream_t stream)
{
    const float* h_user    = (const float*)d_in[0];
    const float* h_item    = (const float*)d_in[1];
    const float* Wself_uu  = (const float*)d_in[2];
    const float* Wneigh_uu = (const float*)d_in[3];
    const float* b_uu      = (const float*)d_in[4];
    const float* Wself_ui  = (const float*)d_in[5];
    const float* Wneigh_ui = (const float*)d_in[6];
    const float* b_ui      = (const float*)d_in[7];
    const float* Wself_iu  = (const float*)d_in[8];
    const float* Wneigh_iu = (const float*)d_in[9];
    const float* b_iu      = (const float*)d_in[10];
    const int* e_uu_src    = (const int*)d_in[11];
    const int* e_uu_dst    = (const int*)d_in[12];
    const int* e_ui_src    = (const int*)d_in[13];
    const int* e_ui_dst    = (const int*)d_in[14];
    const int* e_iu_src    = (const int*)d_in[15];
    const int* e_iu_dst    = (const int*)d_in[16];

    const int NU = in_sizes[0] / D;
    const int NI = in_sizes[1] / D;
    const int E_uu = in_sizes[11];
    const int E_ui = in_sizes[13];
    const int E_iu = in_sizes[15];
    const int ET = E_uu + E_iu + E_ui;

    const int NB0 = (NU + BSZ - 1) / BSZ;   // uu (dst=user)
    const int NB1 = (NU + BSZ - 1) / BSZ;   // iu (dst=user)
    const int NB2 = (NI + BSZ - 1) / BSZ;   // ui (dst=item)
    const int NBT = NB0 + NB1 + NB2;

    // ---- workspace carve-up (16B-aligned chunks) ----
    char* p = (char*)d_ws;
    unsigned short* hbU   = (unsigned short*)p; p += (size_t)NU * D * 2;
    unsigned short* hbI   = (unsigned short*)p; p += (size_t)NI * D * 2;
    unsigned short* accUU = (unsigned short*)p; p += (size_t)NU * D * 2;
    unsigned short* accIU = (unsigned short*)p; p += (size_t)NU * D * 2;
    unsigned short* accUI = (unsigned short*)p; p += (size_t)NI * D * 2;
    short8* WfU0 = (short8*)p; p += 32768;
    short8* WfU1 = (short8*)p; p += 32768;
    short8* WfU2 = (short8*)p; p += 32768;
    short8* WfI0 = (short8*)p; p += 32768;
    short8* WfI1 = (short8*)p; p += 32768;
    float* bsum  = (float*)p;  p += 512;
    int* counts  = (int*)p; p += (size_t)((NBT + 3) & ~3) * 4;
    int* bb      = (int*)p; p += (size_t)((NBT + 4) & ~3) * 4;
    int* cursors = (int*)p; p += (size_t)((NBT + 3) & ~3) * 4;
    int* offsUU  = (int*)p; p += (size_t)NU * 4;
    int* degUU_  = (int*)p; p += (size_t)NU * 4;
    int* offsIU  = (int*)p; p += (size_t)NU * 4;
    int* degIU_  = (int*)p; p += (size_t)NU * 4;
    int* offsUI  = (int*)p; p += (size_t)NI * 4;
    int* degUI_  = (int*)p; p += (size_t)NI * 4;
    int* stg     = (int*)p; p += (size_t)ET * 4;
    int* srt     = (int*)p; p += (size_t)ET * 4;

    // zero only the bucket counters (4.7 KB)
    hipMemsetAsync(counts, 0, (size_t)NBT * sizeof(int), stream);

    const int nCnt0 = (E_uu + CCH - 1) / CCH;
    const int nCnt1 = (E_iu + CCH - 1) / CCH;
    const int nCnt2 = (E_ui + CCH - 1) / CCH;

    hist_kernel<<<nCnt0 + nCnt1 + nCnt2, 256, 0, stream>>>(
        e_uu_dst, E_uu, e_iu_dst, E_iu, e_ui_dst, E_ui,
        counts, NB0, NB1, nCnt0, nCnt1);

    scan_kernel<<<1, 1024, 0, stream>>>(counts, NBT, bb, cursors);

    const int nblk0 = (E_uu + CHUNK - 1) / CHUNK;
    const int nblk1 = (E_iu + CHUNK - 1) / CHUNK;
    const int nblk2 = (E_ui + CHUNK - 1) / CHUNK;
    const int nblkS = nblk0 + nblk1 + nblk2;
    const int nU8 = NU * D / 8, nI8 = NI * D / 8;
    const int nConvH = (nU8 + nI8 + 255) / 256;

    scatter_conv<<<nblkS + nConvH, 256, 0, stream>>>(
        e_uu_src, e_uu_dst, E_uu,
        e_iu_src, e_iu_dst, E_iu,
        e_ui_src, e_ui_dst, E_ui,
        NB0, NB1, cursors, stg, nblk0, nblk1, nblkS,
        h_user, h_item, nU8, nI8, hbU, hbI);

    fill_wpack<<<NBT + 41, 256, 0, stream>>>(
        stg, bb, srt,
        offsUU, degUU_, offsIU, degIU_, offsUI, degUI_,
        NB0, NB1, NU, NI, NBT,
        Wself_uu, Wself_iu, Wneigh_uu, Wneigh_iu, Wself_ui, Wneigh_ui,
        WfU0, WfU1, WfU2, WfI0, WfI1,
        b_uu, b_iu, bsum);

    gather_all<<<(2 * NU + NI + 3) / 4, 256, 0, stream>>>(
        hbU, hbI, srt,
        offsUU, degUU_, offsIU, degIU_, offsUI, degUI_,
        accUU, accIU, accUI, NU, NI);

    float* out_user = (float*)d_out;
    float* out_item = out_user + (size_t)NU * D;
    const int nBlkU = (NU + 127) / 128, nBlkI = (NI + 127) / 128;

    gemm_all<<<nBlkU + nBlkI, 512, 0, stream>>>(
        hbU, accUU, accIU, WfU0, WfU1, WfU2, bsum,
        hbI, accUI, WfI0, WfI1, b_ui,
        out_user, out_item, NU, NI, nBlkU);
}

// Round 9
// 179.514 us; speedup vs baseline: 2.6805x; 1.0083x over previous
//
#include <hip/hip_runtime.h>

#define D 128
#define BSZ 128            // dst nodes per bucket
#define CHUNK 8192         // edges per bucket_scatter block
#define CCH 16384          // edges per hist chunk

typedef __attribute__((ext_vector_type(8))) short short8;
typedef __attribute__((ext_vector_type(4))) float f32x4;
typedef __attribute__((ext_vector_type(2))) float f32x2;

__device__ inline float u2f(unsigned int u) {
    union { unsigned int u; float f; } x; x.u = u; return x.f;
}
__device__ inline unsigned short f2b(float f) {
    union { float f; unsigned int u; } x; x.f = f;
    unsigned int r = x.u + 0x7FFFu + ((x.u >> 16) & 1u);
    return (unsigned short)(r >> 16);
}

// ---------------------------------------------------------------------------
// hist_conv (fused): [0,nCnt) per-bucket edge counts (LDS-privatized) |
// [nCnt,...) h fp32->bf16 conversion. Both fit one block-round on 256 CUs.
// ---------------------------------------------------------------------------
__global__ __launch_bounds__(256) void hist_conv(
    const int* __restrict__ d_uu, int E_uu,
    const int* __restrict__ d_iu, int E_iu,
    const int* __restrict__ d_ui, int E_ui,
    int* __restrict__ counts, int NB0, int NB1, int nCnt0, int nCnt1, int nCnt,
    const float* __restrict__ hU, const float* __restrict__ hI,
    int nU8, int nI8,
    unsigned short* __restrict__ hbU, unsigned short* __restrict__ hbI)
{
    __shared__ int hcnt[512];
    const int t = threadIdx.x;

    if (blockIdx.x >= nCnt) {
        // ---- h conversion: 8 floats per thread ----
        int g = (blockIdx.x - nCnt) * 256 + t;
        const float* src; unsigned short* dst;
        if (g < nU8) { src = hU + (size_t)g * 8; dst = hbU + (size_t)g * 8; }
        else {
            g -= nU8;
            if (g >= nI8) return;
            src = hI + (size_t)g * 8; dst = hbI + (size_t)g * 8;
        }
        const float4 a = *reinterpret_cast<const float4*>(src);
        const float4 c = *reinterpret_cast<const float4*>(src + 4);
        short8 o;
        o[0] = (short)f2b(a.x); o[1] = (short)f2b(a.y);
        o[2] = (short)f2b(a.z); o[3] = (short)f2b(a.w);
        o[4] = (short)f2b(c.x); o[5] = (short)f2b(c.y);
        o[6] = (short)f2b(c.z); o[7] = (short)f2b(c.w);
        *reinterpret_cast<short8*>(dst) = o;
        return;
    }

    int cb = blockIdx.x;
    const int* dstp; int E; int relBase; int c0;
    if (cb < nCnt0)              { dstp = d_uu; E = E_uu; relBase = 0;          c0 = cb; }
    else if (cb < nCnt0 + nCnt1) { dstp = d_iu; E = E_iu; relBase = NB0;        c0 = cb - nCnt0; }
    else                         { dstp = d_ui; E = E_ui; relBase = NB0 + NB1;  c0 = cb - nCnt0 - nCnt1; }

    for (int i = t; i < 512; i += 256) hcnt[i] = 0;
    __syncthreads();
    const int e0 = c0 * CCH;
#pragma unroll 4
    for (int j = 0; j < CCH / 256; ++j) {
        int e = e0 + j * 256 + t;
        if (e < E) atomicAdd(&hcnt[dstp[e] >> 7], 1);
    }
    __syncthreads();
    for (int i = t; i < 512; i += 256) {
        int c = hcnt[i];
        if (c) atomicAdd(&counts[relBase + i], c);
    }
}

// ---------------------------------------------------------------------------
// scan: exclusive scan of counts[NBT] -> bb[NBT+1]; cursors = copy of bases.
// ---------------------------------------------------------------------------
__global__ __launch_bounds__(1024) void scan_kernel(
    const int* __restrict__ counts, int NBT,
    int* __restrict__ bb, int* __restrict__ cur)
{
    __shared__ int s[1024];
    int t = threadIdx.x;
    int i0 = t * 2, i1 = t * 2 + 1;
    int v0 = (i0 < NBT) ? counts[i0] : 0;
    int v1 = (i1 < NBT) ? counts[i1] : 0;
    int sum = v0 + v1;
    s[t] = sum;
    __syncthreads();
    for (int off = 1; off < 1024; off <<= 1) {
        int x = (t >= off) ? s[t - off] : 0;
        __syncthreads();
        s[t] += x;
        __syncthreads();
    }
    int pre = s[t] - sum;   // exclusive prefix
    if (i0 < NBT) { bb[i0] = pre;      cur[i0] = pre; }
    if (i1 < NBT) { bb[i1] = pre + v0; cur[i1] = pre + v0; }
    if (t == 1023) bb[NBT] = s[1023];
}

// ---------------------------------------------------------------------------
// bucket_scatter: group edges by 128-dst bucket into staging (packed int:
// src | dstLocal<<17) via block-aggregated reservations.
// ---------------------------------------------------------------------------
__global__ __launch_bounds__(256) void bucket_scatter(
    const int* __restrict__ s_uu, const int* __restrict__ d_uu, int E_uu,
    const int* __restrict__ s_iu, const int* __restrict__ d_iu, int E_iu,
    const int* __restrict__ s_ui, const int* __restrict__ d_ui, int E_ui,
    int NB0, int NB1,
    int* __restrict__ cursors, int* __restrict__ stg,
    int nblk0, int nblk1)
{
    __shared__ int hist[512];
    __shared__ int bbase[512];
    const int t = threadIdx.x;

    const int* src; const int* dst; int E; int relBase; int b0;
    if (blockIdx.x < nblk0) {
        b0 = blockIdx.x; src = s_uu; dst = d_uu; E = E_uu; relBase = 0;
    } else if (blockIdx.x < nblk0 + nblk1) {
        b0 = blockIdx.x - nblk0; src = s_iu; dst = d_iu; E = E_iu; relBase = NB0;
    } else {
        b0 = blockIdx.x - nblk0 - nblk1; src = s_ui; dst = d_ui; E = E_ui;
        relBase = NB0 + NB1;
    }
    const int e0 = b0 * CHUNK;

    for (int i = t; i < 512; i += 256) hist[i] = 0;
    __syncthreads();

#pragma unroll
    for (int j = 0; j < CHUNK / 256; ++j) {
        int e = e0 + j * 256 + t;
        if (e < E) atomicAdd(&hist[dst[e] >> 7], 1);
    }
    __syncthreads();

    for (int b = t; b < 512; b += 256) {
        int c = hist[b];
        bbase[b] = c ? atomicAdd(&cursors[relBase + b], c) : 0;
        hist[b] = 0;    // reuse as rank counter
    }
    __syncthreads();

#pragma unroll
    for (int j = 0; j < CHUNK / 256; ++j) {
        int e = e0 + j * 256 + t;
        if (e < E) {
            int dv = dst[e];
            int bkt = dv >> 7;
            int r = atomicAdd(&hist[bkt], 1);
            stg[bbase[bkt] + r] = (src[e] & 0x1FFFF) | ((dv & 127) << 17);
        }
    }
}

// ---------------------------------------------------------------------------
// fill_wpack (fused): [0,NBT) csr_fill per bucket (emits packed int2
// {start,deg} per node) | [NBT,NBT+40) W fragment packing | [NBT+40] bias.
// ---------------------------------------------------------------------------
__global__ __launch_bounds__(256) void fill_wpack(
    const int* __restrict__ stg, const int* __restrict__ bb,
    int* __restrict__ srt,
    int2* __restrict__ nfoUU, int2* __restrict__ nfoIU, int2* __restrict__ nfoUI,
    int NB0, int NB1, int NU, int NI, int NBT,
    const float* __restrict__ Wself_uu, const float* __restrict__ Wself_iu,
    const float* __restrict__ Wneigh_uu, const float* __restrict__ Wneigh_iu,
    const float* __restrict__ Wself_ui, const float* __restrict__ Wneigh_ui,
    short8* __restrict__ WfU0, short8* __restrict__ WfU1, short8* __restrict__ WfU2,
    short8* __restrict__ WfI0, short8* __restrict__ WfI1,
    const float* __restrict__ b_uu, const float* __restrict__ b_iu,
    float* __restrict__ bsum)
{
    const int t = threadIdx.x;
    if (blockIdx.x >= NBT) {
        const int wb = blockIdx.x - NBT;
        if (wb < 40) {
            const float* Wa; const float* Wb = nullptr; short8* Wf;
            switch (wb >> 3) {
                case 0: Wa = Wself_uu; Wb = Wself_iu; Wf = WfU0; break;
                case 1: Wa = Wneigh_uu; Wf = WfU1; break;
                case 2: Wa = Wneigh_iu; Wf = WfU2; break;
                case 3: Wa = Wself_ui;  Wf = WfI0; break;
                default: Wa = Wneigh_ui; Wf = WfI1; break;
            }
            int t2 = (wb & 7) * 256 + t;            // 0..2047
            int c  = t2 >> 8;
            int kc = (t2 >> 6) & 3;
            int l  = t2 & 63;
            int n  = c * 16 + (l & 15);
            int k0 = kc * 32 + ((l >> 4) << 3);
            short8 o;
#pragma unroll
            for (int j = 0; j < 8; ++j) {
                float v = Wa[(k0 + j) * D + n];
                if (Wb) v += Wb[(k0 + j) * D + n];
                o[j] = (short)f2b(v);
            }
            Wf[t2] = o;
        } else {
            if (t < D) bsum[t] = b_uu[t] + b_iu[t];
        }
        return;
    }

    __shared__ int cnt[BSZ];
    __shared__ int st[BSZ];
    __shared__ int rank[BSZ];
    __shared__ int sc[BSZ];

    const int b = blockIdx.x;
    int2* nfo; int N; int lb;
    if (b < NB0)            { lb = b;             nfo = nfoUU; N = NU; }
    else if (b < NB0 + NB1) { lb = b - NB0;       nfo = nfoIU; N = NU; }
    else                    { lb = b - NB0 - NB1; nfo = nfoUI; N = NI; }

    const int node0 = lb * BSZ;
    const int bLo = bb[b], bHi = bb[b + 1];

    if (t < BSZ) { cnt[t] = 0; rank[t] = 0; }
    __syncthreads();

    for (int e = bLo + t; e < bHi; e += 256)
        atomicAdd(&cnt[(stg[e] >> 17) & 127], 1);
    __syncthreads();

    if (t < BSZ) sc[t] = cnt[t];
    __syncthreads();
    for (int off = 1; off < BSZ; off <<= 1) {
        int x = 0;
        if (t < BSZ && t >= off) x = sc[t - off];
        __syncthreads();
        if (t < BSZ) sc[t] += x;
        __syncthreads();
    }
    if (t < BSZ) {
        st[t] = sc[t] - cnt[t];
        int node = node0 + t;
        if (node < N) nfo[node] = make_int2(bLo + st[t], cnt[t]);
    }
    __syncthreads();

    for (int e = bLo + t; e < bHi; e += 256) {
        int v = stg[e];
        int nl = (v >> 17) & 127;
        int r = atomicAdd(&rank[nl], 1);
        srt[bLo + st[nl] + r] = v & 0x1FFFF;
    }
}

// ---------------------------------------------------------------------------
// gather (v3): one wave per node. Software-pipelined: next iteration's srt
// indices are loaded before accumulating the current 8 rows. Accumulation
// in f32x2 (packed-add eligible): per u32 (2 bf16): shl, and, pk_add.
// ---------------------------------------------------------------------------
__global__ __launch_bounds__(256) void gather_all(
    const unsigned short* __restrict__ hbU, const unsigned short* __restrict__ hbI,
    const int* __restrict__ srt,
    const int2* __restrict__ nfoUU, const int2* __restrict__ nfoIU,
    const int2* __restrict__ nfoUI,
    unsigned short* __restrict__ accUU, unsigned short* __restrict__ accIU,
    unsigned short* __restrict__ accUI,
    int NU, int NI)
{
    int w = (blockIdx.x * 256 + threadIdx.x) >> 6;
    const int lane = threadIdx.x & 63;

    const unsigned short* hb; const int2* nfo; unsigned short* acc;
    if (w < NU)            { hb = hbU; nfo = nfoUU; acc = accUU; }
    else if (w < 2 * NU)   { w -= NU; hb = hbI; nfo = nfoIU; acc = accIU; }
    else                   { w -= 2 * NU; if (w >= NI) return;
                             hb = hbU; nfo = nfoUI; acc = accUI; }

    const int2 nd   = nfo[w];
    const int start = nd.x;
    const int dg    = nd.y;
    const int end   = start + dg;
    const int part  = lane & 15;
    const int slot  = lane >> 4;
    const unsigned short* hbp = hb + part * 8;

    f32x2 s01[4];
#pragma unroll
    for (int j = 0; j < 4; ++j) s01[j] = (f32x2){0.f, 0.f};

#define ACCUM(U, K) { \
        f32x2 t_; t_[0] = u2f((U) << 16); t_[1] = u2f((U) & 0xFFFF0000u); \
        s01[K] += t_; }
#define ACCUM4(V) { ACCUM(V.x, 0) ACCUM(V.y, 1) ACCUM(V.z, 2) ACCUM(V.w, 3) }

    int base = start;
    bool has = (base + 8 <= end);
    int c0 = 0, c1 = 0;
    if (has) { c0 = srt[base + slot]; c1 = srt[base + 4 + slot]; }
    while (has) {
        const bool hasNext = (base + 16 <= end);
        int n0 = 0, n1 = 0;
        if (hasNext) { n0 = srt[base + 8 + slot]; n1 = srt[base + 12 + slot]; }
        const uint4 v0 = *reinterpret_cast<const uint4*>(hbp + (size_t)c0 * D);
        const uint4 v1 = *reinterpret_cast<const uint4*>(hbp + (size_t)c1 * D);
        ACCUM4(v0);
        ACCUM4(v1);
        c0 = n0; c1 = n1; base += 8; has = hasNext;
    }
    // tail: fewer than 8 rows remain
    {
        const int i0 = base + slot;
        const int i1 = base + 4 + slot;
        if (i0 < end) {
            const uint4 v = *reinterpret_cast<const uint4*>(
                hbp + (size_t)srt[i0] * D);
            ACCUM4(v);
        }
        if (i1 < end) {
            const uint4 v = *reinterpret_cast<const uint4*>(
                hbp + (size_t)srt[i1] * D);
            ACCUM4(v);
        }
    }
#undef ACCUM4
#undef ACCUM

    float s[8];
#pragma unroll
    for (int j = 0; j < 4; ++j) { s[2 * j] = s01[j][0]; s[2 * j + 1] = s01[j][1]; }
#pragma unroll
    for (int j = 0; j < 8; ++j) {
        s[j] += __shfl_xor(s[j], 16);
        s[j] += __shfl_xor(s[j], 32);
    }
    if (slot == 0) {
        const float scale = 1.0f / fmaxf((float)dg, 1.0f);
        short8 o;
#pragma unroll
        for (int j = 0; j < 8; ++j) o[j] = (short)f2b(s[j] * scale);
        *reinterpret_cast<short8*>(acc + (size_t)w * D + part * 8) = o;
    }
}

// ---------------------------------------------------------------------------
// GEMM (fused): both output types in one launch, branch on block range.
// out[N,128] = A0@W0 + A1@W1 [+ A2@W2] + bias; W* fragment-linear bf16.
// ---------------------------------------------------------------------------
__global__ __launch_bounds__(512) void gemm_all(
    const unsigned short* __restrict__ hbU,
    const unsigned short* __restrict__ accUU, const unsigned short* __restrict__ accIU,
    const short8* __restrict__ WfU0, const short8* __restrict__ WfU1,
    const short8* __restrict__ WfU2, const float* __restrict__ bsum,
    const unsigned short* __restrict__ hbI, const unsigned short* __restrict__ accUI,
    const short8* __restrict__ WfI0, const short8* __restrict__ WfI1,
    const float* __restrict__ b_ui,
    float* __restrict__ outU, float* __restrict__ outI,
    int NU, int NI, int nBlkU)
{
    __shared__ short8 lds[2048];     // 32 KB: one fragment-linear W
    const int t = threadIdx.x;
    const int w = t >> 6, l = t & 63;

    const unsigned short *A0, *A1, *A2;
    const short8 *W0, *W1, *W2;
    const float* bias; float* out; int N; int blk;
    if (blockIdx.x < nBlkU) {
        blk = blockIdx.x;
        A0 = hbU; A1 = accUU; A2 = accIU;
        W0 = WfU0; W1 = WfU1; W2 = WfU2;
        bias = bsum; out = outU; N = NU;
    } else {
        blk = blockIdx.x - nBlkU;
        A0 = hbI; A1 = accUI; A2 = nullptr;
        W0 = WfI0; W1 = WfI1; W2 = nullptr;
        bias = b_ui; out = outI; N = NI;
    }

    const int row0 = blk * 128 + w * 16;
    const int arow = row0 + (l & 15);

    f32x4 acc[8];
#pragma unroll
    for (int c = 0; c < 8; ++c) acc[c] = (f32x4){0.f, 0.f, 0.f, 0.f};

    const unsigned short* As[3] = {A0, A1, A2};
    const short8* Wfs[3] = {W0, W1, W2};
    const int nsrc = (A2 != nullptr) ? 3 : 2;

    for (int sI = 0; sI < nsrc; ++sI) {
        __syncthreads();
        const short8* Wg = Wfs[sI];
#pragma unroll
        for (int i = 0; i < 4; ++i) lds[t + i * 512] = Wg[t + i * 512];
        __syncthreads();

        const unsigned short* A = As[sI];
        short8 af[4];
        if (arow < N) {
            const unsigned short* base = A + (size_t)arow * D + ((l >> 4) << 3);
#pragma unroll
            for (int kc = 0; kc < 4; ++kc)
                af[kc] = *reinterpret_cast<const short8*>(base + kc * 32);
        } else {
            short8 z = {0, 0, 0, 0, 0, 0, 0, 0};
#pragma unroll
            for (int kc = 0; kc < 4; ++kc) af[kc] = z;
        }
#pragma unroll
        for (int kc = 0; kc < 4; ++kc)
#pragma unroll
            for (int c = 0; c < 8; ++c)
                acc[c] = __builtin_amdgcn_mfma_f32_16x16x32_bf16(
                    af[kc], lds[(c * 4 + kc) * 64 + l], acc[c], 0, 0, 0);
    }

    const int col = l & 15;
#pragma unroll
    for (int c = 0; c < 8; ++c) {
        float bv = bias[c * 16 + col];
#pragma unroll
        for (int r = 0; r < 4; ++r) {
            int row = row0 + ((l >> 4) << 2) + r;
            if (row < N)
                out[(size_t)row * D + c * 16 + col] = acc[c][r] + bv;
        }
    }
}

// ---------------------------------------------------------------------------
extern "C" void kernel_launch(void* const* d_in, const int* in_sizes, int n_in,
                              void* d_out, int out_size, void* d_ws, size_t ws_size,
                              hipStream_t stream)
{
    const float* h_user    = (const float*)d_in[0];
    const float* h_item    = (const float*)d_in[1];
    const float* Wself_uu  = (const float*)d_in[2];
    const float* Wneigh_uu = (const float*)d_in[3];
    const float* b_uu      = (const float*)d_in[4];
    const float* Wself_ui  = (const float*)d_in[5];
    const float* Wneigh_ui = (const float*)d_in[6];
    const float* b_ui      = (const float*)d_in[7];
    const float* Wself_iu  = (const float*)d_in[8];
    const float* Wneigh_iu = (const float*)d_in[9];
    const float* b_iu      = (const float*)d_in[10];
    const int* e_uu_src    = (const int*)d_in[11];
    const int* e_uu_dst    = (const int*)d_in[12];
    const int* e_ui_src    = (const int*)d_in[13];
    const int* e_ui_dst    = (const int*)d_in[14];
    const int* e_iu_src    = (const int*)d_in[15];
    const int* e_iu_dst    = (const int*)d_in[16];

    const int NU = in_sizes[0] / D;
    const int NI = in_sizes[1] / D;
    const int E_uu = in_sizes[11];
    const int E_ui = in_sizes[13];
    const int E_iu = in_sizes[15];
    const int ET = E_uu + E_iu + E_ui;

    const int NB0 = (NU + BSZ - 1) / BSZ;   // uu (dst=user)
    const int NB1 = (NU + BSZ - 1) / BSZ;   // iu (dst=user)
    const int NB2 = (NI + BSZ - 1) / BSZ;   // ui (dst=item)
    const int NBT = NB0 + NB1 + NB2;

    // ---- workspace carve-up (16B-aligned chunks) ----
    char* p = (char*)d_ws;
    unsigned short* hbU   = (unsigned short*)p; p += (size_t)NU * D * 2;
    unsigned short* hbI   = (unsigned short*)p; p += (size_t)NI * D * 2;
    unsigned short* accUU = (unsigned short*)p; p += (size_t)NU * D * 2;
    unsigned short* accIU = (unsigned short*)p; p += (size_t)NU * D * 2;
    unsigned short* accUI = (unsigned short*)p; p += (size_t)NI * D * 2;
    short8* WfU0 = (short8*)p; p += 32768;
    short8* WfU1 = (short8*)p; p += 32768;
    short8* WfU2 = (short8*)p; p += 32768;
    short8* WfI0 = (short8*)p; p += 32768;
    short8* WfI1 = (short8*)p; p += 32768;
    float* bsum  = (float*)p;  p += 512;
    int* counts  = (int*)p; p += (size_t)((NBT + 3) & ~3) * 4;
    int* bb      = (int*)p; p += (size_t)((NBT + 4) & ~3) * 4;
    int* cursors = (int*)p; p += (size_t)((NBT + 3) & ~3) * 4;
    int2* nfoUU  = (int2*)p; p += (size_t)NU * 8;
    int2* nfoIU  = (int2*)p; p += (size_t)NU * 8;
    int2* nfoUI  = (int2*)p; p += (size_t)NI * 8;
    int* stg     = (int*)p; p += (size_t)ET * 4;
    int* srt     = (int*)p; p += (size_t)ET * 4;

    // zero only the bucket counters (4.7 KB)
    hipMemsetAsync(counts, 0, (size_t)NBT * sizeof(int), stream);

    const int nCnt0 = (E_uu + CCH - 1) / CCH;
    const int nCnt1 = (E_iu + CCH - 1) / CCH;
    const int nCnt2 = (E_ui + CCH - 1) / CCH;
    const int nCnt  = nCnt0 + nCnt1 + nCnt2;
    const int nU8 = NU * D / 8, nI8 = NI * D / 8;
    const int nConvH = (nU8 + nI8 + 255) / 256;

    hist_conv<<<nCnt + nConvH, 256, 0, stream>>>(
        e_uu_dst, E_uu, e_iu_dst, E_iu, e_ui_dst, E_ui,
        counts, NB0, NB1, nCnt0, nCnt1, nCnt,
        h_user, h_item, nU8, nI8, hbU, hbI);

    scan_kernel<<<1, 1024, 0, stream>>>(counts, NBT, bb, cursors);

    const int nblk0 = (E_uu + CHUNK - 1) / CHUNK;
    const int nblk1 = (E_iu + CHUNK - 1) / CHUNK;
    const int nblk2 = (E_ui + CHUNK - 1) / CHUNK;

    bucket_scatter<<<nblk0 + nblk1 + nblk2, 256, 0, stream>>>(
        e_uu_src, e_uu_dst, E_uu,
        e_iu_src, e_iu_dst, E_iu,
        e_ui_src, e_ui_dst, E_ui,
        NB0, NB1, cursors, stg, nblk0, nblk1);

    fill_wpack<<<NBT + 41, 256, 0, stream>>>(
        stg, bb, srt,
        nfoUU, nfoIU, nfoUI,
        NB0, NB1, NU, NI, NBT,
        Wself_uu, Wself_iu, Wneigh_uu, Wneigh_iu, Wself_ui, Wneigh_ui,
        WfU0, WfU1, WfU2, WfI0, WfI1,
        b_uu, b_iu, bsum);

    gather_all<<<(2 * NU + NI + 3) / 4, 256, 0, stream>>>(
        hbU, hbI, srt,
        nfoUU, nfoIU, nfoUI,
        accUU, accIU, accUI, NU, NI);

    float* out_user = (float*)d_out;
    float* out_item = out_user + (size_t)NU * D;
    const int nBlkU = (NU + 127) / 128, nBlkI = (NI + 127) / 128;

    gemm_all<<<nBlkU + nBlkI, 512, 0, stream>>>(
        hbU, accUU, accIU, WfU0, WfU1, WfU2, bsum,
        hbI, accUI, WfI0, WfI1, b_ui,
        out_user, out_item, NU, NI, nBlkU);
}

// Round 10
// 152.866 us; speedup vs baseline: 3.1478x; 1.1743x over previous
//
#include <hip/hip_runtime.h>

#define D 128
#define BSZ 128            // dst nodes per bucket
#define CHUNK 8192         // edges per bucket_scatter block
#define CAPG 6144          // staging slots per bucket (mean ~1536, sigma ~39)
#define SPILL_MAX 65536

typedef __attribute__((ext_vector_type(8))) short short8;
typedef __attribute__((ext_vector_type(4))) float f32x4;
typedef __attribute__((ext_vector_type(2))) float f32x2;

__device__ inline float u2f(unsigned int u) {
    union { unsigned int u; float f; } x; x.u = u; return x.f;
}
__device__ inline unsigned short f2b(float f) {
    union { float f; unsigned int u; } x; x.f = f;
    unsigned int r = x.u + 0x7FFFu + ((x.u >> 16) & 1u);
    return (unsigned short)(r >> 16);
}

// ---------------------------------------------------------------------------
// prep_all (fused, no inter-dependencies):
//   [0, nConvH)          h fp32->bf16 conversion
//   [nConvH, nConvH+40)  W fragment packing
//   [nConvH+40]          bias sum + cursor init + spill counter init
// ---------------------------------------------------------------------------
__global__ __launch_bounds__(256) void prep_all(
    const float* __restrict__ hU, const float* __restrict__ hI,
    int nU8, int nI8,
    unsigned short* __restrict__ hbU, unsigned short* __restrict__ hbI,
    const float* __restrict__ Wself_uu, const float* __restrict__ Wself_iu,
    const float* __restrict__ Wneigh_uu, const float* __restrict__ Wneigh_iu,
    const float* __restrict__ Wself_ui, const float* __restrict__ Wneigh_ui,
    short8* __restrict__ WfU0, short8* __restrict__ WfU1, short8* __restrict__ WfU2,
    short8* __restrict__ WfI0, short8* __restrict__ WfI1,
    const float* __restrict__ b_uu, const float* __restrict__ b_iu,
    float* __restrict__ bsum,
    int* __restrict__ cursors, int* __restrict__ spillCnt,
    int NBT, int nConvH)
{
    const int b = blockIdx.x;
    const int t = threadIdx.x;

    if (b < nConvH) {
        int g = b * 256 + t;
        const float* src; unsigned short* dst;
        if (g < nU8) { src = hU + (size_t)g * 8; dst = hbU + (size_t)g * 8; }
        else {
            g -= nU8;
            if (g >= nI8) return;
            src = hI + (size_t)g * 8; dst = hbI + (size_t)g * 8;
        }
        const float4 a = *reinterpret_cast<const float4*>(src);
        const float4 c = *reinterpret_cast<const float4*>(src + 4);
        short8 o;
        o[0] = (short)f2b(a.x); o[1] = (short)f2b(a.y);
        o[2] = (short)f2b(a.z); o[3] = (short)f2b(a.w);
        o[4] = (short)f2b(c.x); o[5] = (short)f2b(c.y);
        o[6] = (short)f2b(c.z); o[7] = (short)f2b(c.w);
        *reinterpret_cast<short8*>(dst) = o;
        return;
    }
    const int wb = b - nConvH;
    if (wb < 40) {
        const float* Wa; const float* Wb = nullptr; short8* Wf;
        switch (wb >> 3) {
            case 0: Wa = Wself_uu; Wb = Wself_iu; Wf = WfU0; break;
            case 1: Wa = Wneigh_uu; Wf = WfU1; break;
            case 2: Wa = Wneigh_iu; Wf = WfU2; break;
            case 3: Wa = Wself_ui;  Wf = WfI0; break;
            default: Wa = Wneigh_ui; Wf = WfI1; break;
        }
        int t2 = (wb & 7) * 256 + t;            // 0..2047
        int c  = t2 >> 8;
        int kc = (t2 >> 6) & 3;
        int l  = t2 & 63;
        int n  = c * 16 + (l & 15);
        int k0 = kc * 32 + ((l >> 4) << 3);
        short8 o;
#pragma unroll
        for (int j = 0; j < 8; ++j) {
            float v = Wa[(k0 + j) * D + n];
            if (Wb) v += Wb[(k0 + j) * D + n];
            o[j] = (short)f2b(v);
        }
        Wf[t2] = o;
        return;
    }
    // misc block
    if (t < D) bsum[t] = b_uu[t] + b_iu[t];
    for (int i = t; i < NBT; i += 256) cursors[i] = i * CAPG;
    if (t == 0) *spillCnt = 0;
}

// ---------------------------------------------------------------------------
// bucket_scatter: group edges by 128-dst bucket directly into fixed-stride
// bucket windows (packed int: src | dstLocal<<17). Block-aggregated
// reservation; window overflow -> global spill list (correct, ~never taken).
// ---------------------------------------------------------------------------
__global__ __launch_bounds__(256) void bucket_scatter(
    const int* __restrict__ s_uu, const int* __restrict__ d_uu, int E_uu,
    const int* __restrict__ s_iu, const int* __restrict__ d_iu, int E_iu,
    const int* __restrict__ s_ui, const int* __restrict__ d_ui, int E_ui,
    int NB0, int NB1,
    int* __restrict__ cursors, int* __restrict__ stg,
    int2* __restrict__ spill, int* __restrict__ spillCnt,
    int nblk0, int nblk1)
{
    __shared__ int hist[512];
    __shared__ int bbase[512];
    const int t = threadIdx.x;

    const int* src; const int* dst; int E; int relBase; int b0;
    if (blockIdx.x < nblk0) {
        b0 = blockIdx.x; src = s_uu; dst = d_uu; E = E_uu; relBase = 0;
    } else if (blockIdx.x < nblk0 + nblk1) {
        b0 = blockIdx.x - nblk0; src = s_iu; dst = d_iu; E = E_iu; relBase = NB0;
    } else {
        b0 = blockIdx.x - nblk0 - nblk1; src = s_ui; dst = d_ui; E = E_ui;
        relBase = NB0 + NB1;
    }
    const int e0 = b0 * CHUNK;

    for (int i = t; i < 512; i += 256) hist[i] = 0;
    __syncthreads();

#pragma unroll
    for (int j = 0; j < CHUNK / 256; ++j) {
        int e = e0 + j * 256 + t;
        if (e < E) atomicAdd(&hist[dst[e] >> 7], 1);
    }
    __syncthreads();

    for (int b = t; b < 512; b += 256) {
        int c = hist[b];
        bbase[b] = c ? atomicAdd(&cursors[relBase + b], c) : 0;
        hist[b] = 0;    // reuse as rank counter
    }
    __syncthreads();

#pragma unroll
    for (int j = 0; j < CHUNK / 256; ++j) {
        int e = e0 + j * 256 + t;
        if (e < E) {
            int dv = dst[e];
            int bkt = dv >> 7;
            int g = relBase + bkt;
            int r = atomicAdd(&hist[bkt], 1);
            int pos = bbase[bkt] + r;
            int packed = (src[e] & 0x1FFFF) | ((dv & 127) << 17);
            if (pos < (g + 1) * CAPG) {
                stg[pos] = packed;
            } else {
                int si = atomicAdd(spillCnt, 1);
                if (si < SPILL_MAX) spill[si] = make_int2(g, packed);
            }
        }
    }
}

// ---------------------------------------------------------------------------
// gather_bucket: one block per bucket. Counting-sort the bucket's staged
// window into LDS (sidx), then each wave runs the pipelined per-node gather
// (indices served from LDS). deg from LDS counts; spill handled per node.
// ---------------------------------------------------------------------------
__global__ __launch_bounds__(256) void gather_bucket(
    const unsigned short* __restrict__ hbU, const unsigned short* __restrict__ hbI,
    const int* __restrict__ stg, const int* __restrict__ cursors,
    const int2* __restrict__ spill, const int* __restrict__ spillCnt,
    unsigned short* __restrict__ accUU, unsigned short* __restrict__ accIU,
    unsigned short* __restrict__ accUI,
    int NB0, int NB1, int NU, int NI)
{
    __shared__ int sidx[CAPG];      // 24 KB sorted edge sources
    __shared__ int cnt[BSZ];
    __shared__ int st2[BSZ];
    __shared__ int rank[BSZ];
    __shared__ int sc[BSZ];
    __shared__ int spillN_s;

    const int b = blockIdx.x;
    const unsigned short* hb; unsigned short* acc; int N; int lb;
    if (b < NB0)            { lb = b;             hb = hbU; acc = accUU; N = NU; }
    else if (b < NB0 + NB1) { lb = b - NB0;       hb = hbI; acc = accIU; N = NU; }
    else                    { lb = b - NB0 - NB1; hb = hbU; acc = accUI; N = NI; }

    const int t = threadIdx.x;
    const int node0 = lb * BSZ;
    const int base  = b * CAPG;
    const int end   = min(cursors[b], base + CAPG);

    if (t < BSZ) { cnt[t] = 0; rank[t] = 0; }
    if (t == 0) spillN_s = *spillCnt;
    __syncthreads();

    for (int e = base + t; e < end; e += 256)
        atomicAdd(&cnt[(stg[e] >> 17) & 127], 1);
    __syncthreads();

    if (t < BSZ) sc[t] = cnt[t];
    __syncthreads();
    for (int off = 1; off < BSZ; off <<= 1) {
        int x = 0;
        if (t < BSZ && t >= off) x = sc[t - off];
        __syncthreads();
        if (t < BSZ) sc[t] += x;
        __syncthreads();
    }
    if (t < BSZ) st2[t] = sc[t] - cnt[t];
    __syncthreads();

    for (int e = base + t; e < end; e += 256) {
        int v = stg[e];
        int nl = (v >> 17) & 127;
        int r = atomicAdd(&rank[nl], 1);
        sidx[st2[nl] + r] = v & 0x1FFFF;
    }
    __syncthreads();

    const int w = t >> 6, lane = t & 63;
    const int part = lane & 15, slot = lane >> 4;
    const unsigned short* hbp = hb + part * 8;
    const int spillN = spillN_s;

#define ACCUM(U, K) { \
        f32x2 t_; t_[0] = u2f((U) << 16); t_[1] = u2f((U) & 0xFFFF0000u); \
        s01[K] += t_; }
#define ACCUM4(V) { ACCUM(V.x, 0) ACCUM(V.y, 1) ACCUM(V.z, 2) ACCUM(V.w, 3) }

    for (int k = 0; k < 32; ++k) {
        const int nl = w * 32 + k;
        const int node = node0 + nl;
        if (node >= N) break;
        const int mst = st2[nl];
        const int m   = cnt[nl];

        f32x2 s01[4];
#pragma unroll
        for (int j = 0; j < 4; ++j) s01[j] = (f32x2){0.f, 0.f};

        int i = 0;
        bool has = (8 <= m);
        int c0 = 0, c1 = 0;
        if (has) { c0 = sidx[mst + slot]; c1 = sidx[mst + 4 + slot]; }
        while (has) {
            const bool hn = (i + 16 <= m);
            int n0 = 0, n1 = 0;
            if (hn) { n0 = sidx[mst + i + 8 + slot]; n1 = sidx[mst + i + 12 + slot]; }
            const uint4 v0 = *reinterpret_cast<const uint4*>(hbp + (size_t)c0 * D);
            const uint4 v1 = *reinterpret_cast<const uint4*>(hbp + (size_t)c1 * D);
            ACCUM4(v0);
            ACCUM4(v1);
            c0 = n0; c1 = n1; i += 8; has = hn;
        }
        // tail (< 8 rows)
        if (i + slot < m) {
            const uint4 v = *reinterpret_cast<const uint4*>(
                hbp + (size_t)sidx[mst + i + slot] * D);
            ACCUM4(v);
        }
        if (i + 4 + slot < m) {
            const uint4 v = *reinterpret_cast<const uint4*>(
                hbp + (size_t)sidx[mst + i + 4 + slot] * D);
            ACCUM4(v);
        }

        int deg = m;
        if (spillN) {      // ~never taken; correctness fallback
            for (int q = 0; q < spillN; ++q) {
                int2 e = spill[q];
                if (e.x == b && ((e.y >> 17) & 127) == nl) {
                    if (slot == 0) {
                        const uint4 v = *reinterpret_cast<const uint4*>(
                            hbp + (size_t)(e.y & 0x1FFFF) * D);
                        ACCUM4(v);
                    }
                    ++deg;
                }
            }
        }

        float s[8];
#pragma unroll
        for (int j = 0; j < 4; ++j) { s[2 * j] = s01[j][0]; s[2 * j + 1] = s01[j][1]; }
#pragma unroll
        for (int j = 0; j < 8; ++j) {
            s[j] += __shfl_xor(s[j], 16);
            s[j] += __shfl_xor(s[j], 32);
        }
        if (slot == 0) {
            const float scale = 1.0f / fmaxf((float)deg, 1.0f);
            short8 o;
#pragma unroll
            for (int j = 0; j < 8; ++j) o[j] = (short)f2b(s[j] * scale);
            *reinterpret_cast<short8*>(acc + (size_t)node * D + part * 8) = o;
        }
    }
#undef ACCUM4
#undef ACCUM
}

// ---------------------------------------------------------------------------
// GEMM (fused): both output types in one launch, branch on block range.
// out[N,128] = A0@W0 + A1@W1 [+ A2@W2] + bias; W* fragment-linear bf16.
// ---------------------------------------------------------------------------
__global__ __launch_bounds__(512) void gemm_all(
    const unsigned short* __restrict__ hbU,
    const unsigned short* __restrict__ accUU, const unsigned short* __restrict__ accIU,
    const short8* __restrict__ WfU0, const short8* __restrict__ WfU1,
    const short8* __restrict__ WfU2, const float* __restrict__ bsum,
    const unsigned short* __restrict__ hbI, const unsigned short* __restrict__ accUI,
    const short8* __restrict__ WfI0, const short8* __restrict__ WfI1,
    const float* __restrict__ b_ui,
    float* __restrict__ outU, float* __restrict__ outI,
    int NU, int NI, int nBlkU)
{
    __shared__ short8 lds[2048];     // 32 KB: one fragment-linear W
    const int t = threadIdx.x;
    const int w = t >> 6, l = t & 63;

    const unsigned short *A0, *A1, *A2;
    const short8 *W0, *W1, *W2;
    const float* bias; float* out; int N; int blk;
    if (blockIdx.x < nBlkU) {
        blk = blockIdx.x;
        A0 = hbU; A1 = accUU; A2 = accIU;
        W0 = WfU0; W1 = WfU1; W2 = WfU2;
        bias = bsum; out = outU; N = NU;
    } else {
        blk = blockIdx.x - nBlkU;
        A0 = hbI; A1 = accUI; A2 = nullptr;
        W0 = WfI0; W1 = WfI1; W2 = nullptr;
        bias = b_ui; out = outI; N = NI;
    }

    const int row0 = blk * 128 + w * 16;
    const int arow = row0 + (l & 15);

    f32x4 acc[8];
#pragma unroll
    for (int c = 0; c < 8; ++c) acc[c] = (f32x4){0.f, 0.f, 0.f, 0.f};

    const unsigned short* As[3] = {A0, A1, A2};
    const short8* Wfs[3] = {W0, W1, W2};
    const int nsrc = (A2 != nullptr) ? 3 : 2;

    for (int sI = 0; sI < nsrc; ++sI) {
        __syncthreads();
        const short8* Wg = Wfs[sI];
#pragma unroll
        for (int i = 0; i < 4; ++i) lds[t + i * 512] = Wg[t + i * 512];
        __syncthreads();

        const unsigned short* A = As[sI];
        short8 af[4];
        if (arow < N) {
            const unsigned short* base = A + (size_t)arow * D + ((l >> 4) << 3);
#pragma unroll
            for (int kc = 0; kc < 4; ++kc)
                af[kc] = *reinterpret_cast<const short8*>(base + kc * 32);
        } else {
            short8 z = {0, 0, 0, 0, 0, 0, 0, 0};
#pragma unroll
            for (int kc = 0; kc < 4; ++kc) af[kc] = z;
        }
#pragma unroll
        for (int kc = 0; kc < 4; ++kc)
#pragma unroll
            for (int c = 0; c < 8; ++c)
                acc[c] = __builtin_amdgcn_mfma_f32_16x16x32_bf16(
                    af[kc], lds[(c * 4 + kc) * 64 + l], acc[c], 0, 0, 0);
    }

    const int col = l & 15;
#pragma unroll
    for (int c = 0; c < 8; ++c) {
        float bv = bias[c * 16 + col];
#pragma unroll
        for (int r = 0; r < 4; ++r) {
            int row = row0 + ((l >> 4) << 2) + r;
            if (row < N)
                out[(size_t)row * D + c * 16 + col] = acc[c][r] + bv;
        }
    }
}

// ---------------------------------------------------------------------------
extern "C" void kernel_launch(void* const* d_in, const int* in_sizes, int n_in,
                              void* d_out, int out_size, void* d_ws, size_t ws_size,
                              hipStream_t stream)
{
    const float* h_user    = (const float*)d_in[0];
    const float* h_item    = (const float*)d_in[1];
    const float* Wself_uu  = (const float*)d_in[2];
    const float* Wneigh_uu = (const float*)d_in[3];
    const float* b_uu      = (const float*)d_in[4];
    const float* Wself_ui  = (const float*)d_in[5];
    const float* Wneigh_ui = (const float*)d_in[6];
    const float* b_ui      = (const float*)d_in[7];
    const float* Wself_iu  = (const float*)d_in[8];
    const float* Wneigh_iu = (const float*)d_in[9];
    const float* b_iu      = (const float*)d_in[10];
    const int* e_uu_src    = (const int*)d_in[11];
    const int* e_uu_dst    = (const int*)d_in[12];
    const int* e_ui_src    = (const int*)d_in[13];
    const int* e_ui_dst    = (const int*)d_in[14];
    const int* e_iu_src    = (const int*)d_in[15];
    const int* e_iu_dst    = (const int*)d_in[16];

    const int NU = in_sizes[0] / D;
    const int NI = in_sizes[1] / D;
    const int E_uu = in_sizes[11];
    const int E_ui = in_sizes[13];
    const int E_iu = in_sizes[15];

    const int NB0 = (NU + BSZ - 1) / BSZ;   // uu (dst=user)
    const int NB1 = (NU + BSZ - 1) / BSZ;   // iu (dst=user)
    const int NB2 = (NI + BSZ - 1) / BSZ;   // ui (dst=item)
    const int NBT = NB0 + NB1 + NB2;

    // ---- workspace carve-up (16B-aligned chunks) ----
    char* p = (char*)d_ws;
    unsigned short* hbU   = (unsigned short*)p; p += (size_t)NU * D * 2;
    unsigned short* hbI   = (unsigned short*)p; p += (size_t)NI * D * 2;
    unsigned short* accUU = (unsigned short*)p; p += (size_t)NU * D * 2;
    unsigned short* accIU = (unsigned short*)p; p += (size_t)NU * D * 2;
    unsigned short* accUI = (unsigned short*)p; p += (size_t)NI * D * 2;
    short8* WfU0 = (short8*)p; p += 32768;
    short8* WfU1 = (short8*)p; p += 32768;
    short8* WfU2 = (short8*)p; p += 32768;
    short8* WfI0 = (short8*)p; p += 32768;
    short8* WfI1 = (short8*)p; p += 32768;
    float* bsum  = (float*)p;  p += 512;
    int* cursors = (int*)p; p += (size_t)((NBT + 3) & ~3) * 4;
    int* spillCnt = (int*)p; p += 16;
    int2* spill  = (int2*)p; p += (size_t)SPILL_MAX * 8;
    int* stg     = (int*)p; p += (size_t)NBT * CAPG * 4;

    const int nU8 = NU * D / 8, nI8 = NI * D / 8;
    const int nConvH = (nU8 + nI8 + 255) / 256;

    prep_all<<<nConvH + 41, 256, 0, stream>>>(
        h_user, h_item, nU8, nI8, hbU, hbI,
        Wself_uu, Wself_iu, Wneigh_uu, Wneigh_iu, Wself_ui, Wneigh_ui,
        WfU0, WfU1, WfU2, WfI0, WfI1,
        b_uu, b_iu, bsum,
        cursors, spillCnt, NBT, nConvH);

    const int nblk0 = (E_uu + CHUNK - 1) / CHUNK;
    const int nblk1 = (E_iu + CHUNK - 1) / CHUNK;
    const int nblk2 = (E_ui + CHUNK - 1) / CHUNK;

    bucket_scatter<<<nblk0 + nblk1 + nblk2, 256, 0, stream>>>(
        e_uu_src, e_uu_dst, E_uu,
        e_iu_src, e_iu_dst, E_iu,
        e_ui_src, e_ui_dst, E_ui,
        NB0, NB1, cursors, stg, spill, spillCnt, nblk0, nblk1);

    gather_bucket<<<NBT, 256, 0, stream>>>(
        hbU, hbI, stg, cursors, spill, spillCnt,
        accUU, accIU, accUI, NB0, NB1, NU, NI);

    float* out_user = (float*)d_out;
    float* out_item = out_user + (size_t)NU * D;
    const int nBlkU = (NU + 127) / 128, nBlkI = (NI + 127) / 128;

    gemm_all<<<nBlkU + nBlkI, 512, 0, stream>>>(
        hbU, accUU, accIU, WfU0, WfU1, WfU2, bsum,
        hbI, accUI, WfI0, WfI1, b_ui,
        out_user, out_item, NU, NI, nBlkU);
}